// Round 15
// baseline (361.206 us; speedup 1.0000x reference)
//
#include <hip/hip_runtime.h>
#include <math.h>

#define B 4096
#define D 512
#define TOPK 32
#define MCAP 2048

constexpr float OT_EPS_F = 0.05f;
constexpr float FLOORK   = 1e-12f;
constexpr float AMASS    = 1.0f / 4096.0f;   // exact 2^-12
constexpr float TAU      = 1.8f;             // k1 candidate prefilter threshold
constexpr float EPS_C    = 3.814697e-6f;     // 2^-18 convergence tolerance
constexpr float CPRE     = 1.45f;            // conservative cost prefilter (fallback path)
constexpr float CTHR     = 1.3815510f;       // analytic: e>1e-12 <=> c < 0.05*ln(1e12)

// fast softplus via HW transcendentals (v_exp_f32 / v_log_f32), ~1e-7 abs err
__device__ __forceinline__ float softplusf(float x) {
    return fmaxf(x, 0.0f) + __logf(1.0f + __expf(-fabsf(x)));
}
__device__ __forceinline__ unsigned int fkey(float f) {
    unsigned int x = __float_as_uint(f);
    return x ^ ((x & 0x80000000u) ? 0xFFFFFFFFu : 0x80000000u);
}
__device__ __forceinline__ float finv(unsigned int k) {
    unsigned int x = (k & 0x80000000u) ? (k ^ 0x80000000u) : ~k;
    return __uint_as_float(x);
}
__device__ __forceinline__ float rcpf_(float x) { return __builtin_amdgcn_rcpf(x); }
__device__ __forceinline__ void lgkm0() {
    asm volatile("s_waitcnt lgkmcnt(0)" ::: "memory");
    __builtin_amdgcn_sched_barrier(0);
}
__device__ __forceinline__ void vm0() {
    asm volatile("s_waitcnt vmcnt(0)" ::: "memory");
}
#define DPPADD(x, ctrl) ((x) + __int_as_float(__builtin_amdgcn_update_dpp(0, __float_as_int(x), (ctrl), 0xf, 0xf, false)))
__device__ __forceinline__ float wsum64(float x) {
    x = DPPADD(x, 0x111);
    x = DPPADD(x, 0x112);
    x = DPPADD(x, 0x114);
    x = DPPADD(x, 0x118);
    x = DPPADD(x, 0x142);
    x = DPPADD(x, 0x143);
    return __int_as_float(__builtin_amdgcn_readlane(__float_as_int(x), 63));
}

// ---------------------------------------------------------------------------
// k1: wave-per-row (4 rows / 256-block). HW-transcendental softplus, ballot
// top-32, VALUE-DESCENDING emission (LDS stage + 32-way rank sort) so kmid's
// prefix property holds by construction.
// ---------------------------------------------------------------------------
__global__ __launch_bounds__(256) void k1_row(const float* __restrict__ logits,
                                              const float* __restrict__ text,
                                              const float* __restrict__ image,
                                              const float* __restrict__ bias_p,
                                              float* __restrict__ rowsum,
                                              unsigned int* __restrict__ rowmaxk,
                                              int* __restrict__ top_idx,
                                              float* __restrict__ top_z,
                                              float* __restrict__ ratio,
                                              unsigned int* __restrict__ flags) {
    __shared__ unsigned int candk[4][128];
    __shared__ unsigned int candi[4][128];
    __shared__ unsigned int wcnt[4];
    __shared__ unsigned int skk[4][32];
    __shared__ unsigned int ski[4][32];

    const int tid = threadIdx.x, w = tid >> 6, lane = tid & 63;
    const int row = (blockIdx.x << 2) + w;
    const float bias = bias_p[0];
    const float* lr = logits + (size_t)row * B;
    const float4* lr4 = (const float4*)lr;

    if (lane == 0) wcnt[w] = 0;
    candk[w][lane] = 0; candk[w][lane + 64] = 0;

    float lsum = 0.0f, lmax = -INFINITY;
    bool ovf = false;

// softplus(-z) == softplus(z) - z exactly (same fp path in our formula)
#define K1ELEM(ZV, CC) do {                                                   \
        float z_ = (ZV) + bias;                                               \
        bool dg_ = ((CC) == row);                                             \
        float sp_ = softplusf(z_);                                            \
        lsum += dg_ ? (sp_ - z_) : sp_;                                       \
        float zm_ = dg_ ? -INFINITY : z_;                                     \
        lmax = fmaxf(lmax, zm_);                                              \
        if (zm_ > TAU) {                                                      \
            unsigned int p_ = atomicAdd(&wcnt[w], 1u);                        \
            if (p_ < 128u) { candk[w][p_] = __float_as_uint(z_);              \
                             candi[w][p_] = (unsigned int)(CC); }             \
            else ovf = true;                                                  \
        } } while (0)

    #pragma unroll
    for (int t = 0; t < 16; ++t) {
        float4 z4 = lr4[lane + (t << 6)];
        int cb = (lane << 2) + (t << 8);
        K1ELEM(z4.x, cb);
        K1ELEM(z4.y, cb + 1);
        K1ELEM(z4.z, cb + 2);
        K1ELEM(z4.w, cb + 3);
    }
#undef K1ELEM
    __syncthreads();

    for (int o = 1; o < 64; o <<= 1) {
        lsum += __shfl_xor(lsum, o);
        lmax = fmaxf(lmax, __shfl_xor(lmax, o));
    }
    if (lane == 0) { rowsum[row] = lsum; rowmaxk[row] = fkey(lmax); }

    const unsigned int n = wcnt[w];
    bool fb = (n < (unsigned)TOPK) || (n > 128u) || (__ballot(ovf) != 0ull);

    const unsigned int c0k = candk[w][lane], c1k = candk[w][lane + 64];
    const unsigned int i0  = candi[w][lane], i1  = candi[w][lane + 64];

    if (!fb) {
        // ballot binary search for rank-32 key (raw positive-float bits)
        unsigned int K = 0u;
        for (int b = 31; b >= 0; --b) {
            unsigned int tr = K | (1u << b);
            int cnt = __popcll(__ballot(c0k >= tr)) + __popcll(__ballot(c1k >= tr));
            if (cnt >= TOPK) K = tr;
        }
        unsigned long long m0g = __ballot(c0k > K), m1g = __ballot(c1k > K);
        unsigned long long m0e = __ballot(c0k == K), m1e = __ballot(c1k == K);
        int cnt_gt = __popcll(m0g) + __popcll(m1g);
        int kneed  = TOPK - cnt_gt;
        int eqc    = __popcll(m0e) + __popcll(m1e);
        if (eqc != kneed) {
            fb = true;   // boundary ties -> exact fallback
        } else {
            unsigned long long lmlt = (1ull << lane) - 1ull;
            // stage into per-wave LDS (slot-ranked), then value-sort emit
            int r0 = __popcll(m0g & lmlt);
            if (c0k > K) { skk[w][r0] = c0k; ski[w][r0] = i0; }
            int r1 = __popcll(m0g) + __popcll(m1g & lmlt);
            if (c1k > K) { skk[w][r1] = c1k; ski[w][r1] = i1; }
            int e0 = cnt_gt + __popcll(m0e & lmlt);
            if (c0k == K) { skk[w][e0] = c0k; ski[w][e0] = i0; }
            int e1 = cnt_gt + __popcll(m0e) + __popcll(m1e & lmlt);
            if (c1k == K) { skk[w][e1] = c1k; ski[w][e1] = i1; }
            lgkm0();   // in-wave LDS ordering
            if (lane < 32) {
                unsigned int my = skk[w][lane], mi = ski[w][lane];
                int rk = 0;
                #pragma unroll
                for (int k = 0; k < 32; ++k) {
                    unsigned int ok = skk[w][k];
                    rk += (int)((ok > my) || (ok == my && k < lane));
                }
                size_t rb = (size_t)row * TOPK;
                top_idx[rb + rk] = (int)mi;
                top_z [rb + rk] = __uint_as_float(my);
            }
        }
    }
    if (fb && lane == 0) flags[row] = 1u;

    // ---- fused ratio sample ----
    unsigned int hh = (unsigned int)row * 2654435761u;
    int j = (int)(((unsigned int)row + 1u + (hh % 4095u)) & 4095u);   // j != row
    const float4* tr4 = (const float4*)(text + (size_t)row * D);
    const float4* ir4 = (const float4*)(image + (size_t)j * D);
    float4 a0 = tr4[lane], b0 = ir4[lane];
    float4 a1 = tr4[lane + 64], b1 = ir4[lane + 64];
    float s3 = a0.x * b0.x + a0.y * b0.y + a0.z * b0.z + a0.w * b0.w
             + a1.x * b1.x + a1.y * b1.y + a1.z * b1.z + a1.w * b1.w;
    for (int o = 1; o < 64; o <<= 1) s3 += __shfl_xor(s3, o);
    if (lane == 0) ratio[row] = lr[j] / (s3 + 1e-8f);
}

// ---------------------------------------------------------------------------
// k1f: exact fallback for flagged rows (LDS radix select) + final value sort.
// Normally no-op.
// ---------------------------------------------------------------------------
__global__ __launch_bounds__(256) void k1_fallback(const float* __restrict__ logits,
                                                   const float* __restrict__ bias_p,
                                                   const unsigned int* __restrict__ flags,
                                                   int* __restrict__ top_idx,
                                                   float* __restrict__ top_z) {
    const int row = blockIdx.x;
    if (flags[row] == 0u) return;

    __shared__ unsigned int skey[B];
    __shared__ unsigned int histm[4 * 257 + 4];
    __shared__ unsigned int selb, selk;
    __shared__ int cnt_gt, cnt_eq;
    __shared__ int eqi[64];
    __shared__ unsigned int sk2[32], si2[32];

    const int tid = threadIdx.x, wid = tid >> 6, lane = tid & 63;
    const float bias = bias_p[0];
    const float* lr = logits + (size_t)row * B;

    #pragma unroll
    for (int t = 0; t < 16; ++t) {
        int c = tid + (t << 8);
        float z = lr[c] + bias;
        skey[c] = fkey((c == row) ? -INFINITY : z);
    }
    if (tid == 0) { cnt_gt = 0; cnt_eq = 0; }
    __syncthreads();

    unsigned int prefix = 0, kneed = TOPK;
    for (int r = 0; r < 4; ++r) {
        for (int i = tid; i < 4 * 257 + 4; i += 256) histm[i] = 0;
        __syncthreads();
        const int shift = 24 - 8 * r;
        #pragma unroll
        for (int t = 0; t < 16; ++t) {
            int c = tid + (t << 8);
            unsigned int kx = skey[c];
            bool part = (r == 0) || ((kx >> (32 - 8 * r)) == prefix);
            if (part) atomicAdd(&histm[wid * 257 + ((kx >> shift) & 255u)], 1u);
        }
        __syncthreads();
        unsigned int h = histm[tid] + histm[257 + tid] + histm[514 + tid] + histm[771 + tid];
        unsigned int s = h;
        for (int off = 1; off < 64; off <<= 1) {
            unsigned int o = __shfl_down(s, off);
            if (lane + off < 64) s += o;
        }
        if (lane == 0) histm[1028 + wid] = s;
        __syncthreads();
        unsigned int coarse = 0;
        for (int ww = wid + 1; ww < 4; ++ww) coarse += histm[1028 + ww];
        unsigned int incl = s + coarse, strict = incl - h;
        if (strict < kneed && kneed <= incl) { selb = (unsigned int)tid; selk = kneed - strict; }
        __syncthreads();
        prefix = (prefix << 8) | selb;
        kneed = selk;
        __syncthreads();
    }
    const unsigned int K32 = prefix;

    #pragma unroll
    for (int t = 0; t < 16; ++t) {
        int c = tid + (t << 8);
        unsigned int kx = skey[c];
        if (kx > K32) {
            int p = atomicAdd(&cnt_gt, 1);
            top_idx[(size_t)row * TOPK + p] = c;
            top_z [(size_t)row * TOPK + p] = finv(kx);
        } else if (kx == K32) {
            int p = atomicAdd(&cnt_eq, 1);
            if (p < 64) eqi[p] = c;
        }
    }
    __syncthreads();
    if (tid == 0) {
        int q = (int)kneed, base = cnt_gt, E = cnt_eq;
        float zv = finv(K32);
        if (E <= 64) {
            for (int s2 = 0; s2 < q; ++s2) {
                int best = 0x7FFFFFFF, bp = 0;
                for (int e = 0; e < E; ++e) { int ix = eqi[e]; if (ix < best) { best = ix; bp = e; } }
                eqi[bp] = 0x7FFFFFFF;
                top_idx[(size_t)row * TOPK + base + s2] = best;
                top_z [(size_t)row * TOPK + base + s2] = zv;
            }
        } else {
            int taken = 0;
            for (int c = 0; c < B && taken < q; ++c)
                if (skey[c] == K32) {
                    top_idx[(size_t)row * TOPK + base + taken] = c;
                    top_z [(size_t)row * TOPK + base + taken] = zv;
                    ++taken;
                }
        }
    }
    __syncthreads();   // drains global writes before re-read
    if (tid < 32) {
        sk2[tid] = fkey(top_z[(size_t)row * TOPK + tid]);
        si2[tid] = (unsigned int)top_idx[(size_t)row * TOPK + tid];
    }
    __syncthreads();
    if (tid < 32) {
        unsigned int my = sk2[tid], mi = si2[tid];
        int rk = 0;
        #pragma unroll
        for (int k = 0; k < 32; ++k) {
            unsigned int ok = sk2[k];
            rk += (int)((ok > my) || (ok == my && k < tid));
        }
        top_idx[(size_t)row * TOPK + rk] = (int)mi;
        top_z [(size_t)row * TOPK + rk] = finv(my);
    }
}

// ---------------------------------------------------------------------------
// kmid: fused reduce + CSR build (vectorized, 4-wave) + SINGLE-WAVE Sinkhorn
// (lgkm fences only — measured ~0.5 µs/barrier penalty in single-block
// dispatches makes multi-wave barriered loops slower). m <= 2048.
// ---------------------------------------------------------------------------
__global__ __launch_bounds__(256) void kmid(const float* __restrict__ rowsum,
                                            const unsigned int* __restrict__ rowmaxk,
                                            const float* __restrict__ top_z,
                                            const int* __restrict__ top_idx,
                                            unsigned int* __restrict__ Mkey_g,
                                            double* __restrict__ base_acc_g,
                                            unsigned int* __restrict__ mcount_g,
                                            unsigned int* __restrict__ meta_g,
                                            float* __restrict__ vout) {
    __shared__ __align__(16) unsigned char SB[94208];
    float*  rcsr_val = (float*)(SB + 0);
    float*  ccsr_val = (float*)(SB + 8192);
    float*  arr      = (float*)(SB + 16384);
    float*  usm      = (float*)(SB + 24576);
    float*  vsm      = (float*)(SB + 32768);
    unsigned* aRowSC = (unsigned*)(SB + 40960);
    unsigned* aColSC = (unsigned*)(SB + 49152);
    unsigned short* rcsr_cid = (unsigned short*)(SB + 57344);
    unsigned short* ccsr_rid = (unsigned short*)(SB + 61440);
    unsigned short* aColJ    = (unsigned short*)(SB + 65536);
    unsigned* colPS  = (unsigned*)(SB + 69632);
    unsigned short* rowCnt = (unsigned short*)(SB + 86016);
    unsigned* colCnt  = (unsigned*)(SB + 0);                // build overlay
    unsigned* rowPS   = (unsigned*)(SB + 24576);            // build overlay
    unsigned* colFill = (unsigned*)(SB + 16384);            // build overlay

    __shared__ double sdbl[4];
    __shared__ unsigned smax4[4];
    __shared__ float sMf;
    __shared__ unsigned mTot;
    __shared__ unsigned wq[4];
    __shared__ unsigned nrS, ncS;

    const int tid = threadIdx.x, lane = tid & 63, wv = tid >> 6;

    // ---------- A: reduce ----------
    {
        double s = 0.0; unsigned mk = 0u;
        #pragma unroll
        for (int t = 0; t < 16; ++t) {
            int i = tid + (t << 8);
            s += (double)rowsum[i];
            unsigned k = rowmaxk[i];
            mk = (k > mk) ? k : mk;
        }
        for (int o = 1; o < 64; o <<= 1) {
            s += __shfl_xor(s, o);
            unsigned om = __shfl_xor(mk, o);
            mk = (om > mk) ? om : mk;
        }
        if (lane == 0) { sdbl[wv] = s; smax4[wv] = mk; }
        if (tid == 0) mTot = 0u;
    }
    __syncthreads();
    if (tid == 0) {
        *base_acc_g = sdbl[0] + sdbl[1] + sdbl[2] + sdbl[3];
        unsigned m2 = max(max(smax4[0], smax4[1]), max(smax4[2], smax4[3]));
        *Mkey_g = m2;
        sMf = finv(m2);
    }
    __syncthreads();
    const float M = sMf;
    const float zthr = M - CTHR;

    // ---------- B1: vectorized survivor count + col histogram ----------
    for (int i = tid; i < 4096; i += 256) colCnt[i] = 0u;
    __syncthreads();
    {
        unsigned myTot = 0;
        for (int i = 0; i < 16; ++i) {
            int r = (tid << 4) + i;
            const float4* tz4 = (const float4*)(top_z + (size_t)r * TOPK);
            int cnt = 0;
            #pragma unroll
            for (int q = 0; q < 8; ++q) {
                float4 t = tz4[q];
                cnt += (t.x > zthr) + (t.y > zthr) + (t.z > zthr) + (t.w > zthr);
            }
            rowCnt[r] = (unsigned short)cnt;
            myTot += (unsigned)cnt;
            const int* tj = top_idx + (size_t)r * TOPK;
            for (int k = 0; k < cnt; ++k)
                atomicAdd(&colCnt[(unsigned)tj[k]], 1u);
        }
        atomicAdd(&mTot, myTot);
    }
    __syncthreads();
    const int m = (int)mTot;
    if (tid == 0) { mcount_g[0] = (unsigned)m; meta_g[0] = (m > MCAP) ? 1u : 0u; }
    if (m > MCAP) return;

    // ---------- B2a: row scan ----------
    {
        unsigned pre[16]; unsigned tsum = 0;
        #pragma unroll
        for (int i = 0; i < 16; ++i) {
            unsigned c2 = rowCnt[(tid << 4) + i];
            unsigned val = c2 | ((c2 ? 1u : 0u) << 16);
            pre[i] = tsum; tsum += val;
        }
        unsigned sc = tsum;
        for (int o = 1; o < 64; o <<= 1) {
            unsigned n2 = __shfl_up(sc, o);
            if (lane >= o) sc += n2;
        }
        if (lane == 63) wq[wv] = sc;
        __syncthreads();
        unsigned woff = 0;
        for (int w2 = 0; w2 < wv; ++w2) woff += wq[w2];
        unsigned base0 = woff + sc - tsum;
        #pragma unroll
        for (int i = 0; i < 16; ++i) {
            int r = (tid << 4) + i;
            unsigned pfx = base0 + pre[i];
            rowPS[r] = pfx;
            unsigned c2 = rowCnt[r];
            if (c2) aRowSC[pfx >> 16] = (pfx & 0xFFFFu) | (c2 << 16);
        }
        if (tid == 255) nrS = (base0 + tsum) >> 16;
    }
    __syncthreads();
    // ---------- B2b: col scan ----------
    {
        unsigned pre[16]; unsigned tsum = 0;
        #pragma unroll
        for (int i = 0; i < 16; ++i) {
            unsigned c2 = colCnt[(tid << 4) + i];
            unsigned val = c2 | ((c2 ? 1u : 0u) << 16);
            pre[i] = tsum; tsum += val;
        }
        unsigned sc = tsum;
        for (int o = 1; o < 64; o <<= 1) {
            unsigned n2 = __shfl_up(sc, o);
            if (lane >= o) sc += n2;
        }
        if (lane == 63) wq[wv] = sc;
        __syncthreads();
        unsigned woff = 0;
        for (int w2 = 0; w2 < wv; ++w2) woff += wq[w2];
        unsigned base0 = woff + sc - tsum;
        #pragma unroll
        for (int i = 0; i < 16; ++i) {
            int j = (tid << 4) + i;
            unsigned pfx = base0 + pre[i];
            colPS[j] = pfx;
            unsigned c2 = colCnt[j];
            if (c2) {
                unsigned cc = pfx >> 16;
                aColSC[cc] = (pfx & 0xFFFFu) | (c2 << 16);
                aColJ[cc] = (unsigned short)j;
            }
        }
        if (tid == 255) ncS = (base0 + tsum) >> 16;
    }
    __syncthreads();
    {   // max col count guard (cnt must fit packing; conservative 64)
        unsigned mcc = 0;
        #pragma unroll
        for (int i = 0; i < 16; ++i) mcc = max(mcc, colCnt[(tid << 4) + i]);
        for (int o = 1; o < 64; o <<= 1) { unsigned t2 = __shfl_xor(mcc, o); mcc = max(mcc, t2); }
        if (lane == 0) smax4[wv] = mcc;
    }
    __syncthreads();
    {
        unsigned mx = max(max(smax4[0], smax4[1]), max(smax4[2], smax4[3]));
        if (tid == 0 && mx > 64u) meta_g[0] = 1u;
        if (mx > 64u) return;   // uniform
    }

    // ---------- B3: fill CSR ----------
    for (int i = tid; i < 2048; i += 256) colFill[i] = 0u;
    __syncthreads();
    for (int i = 0; i < 16; ++i) {
        int r = (tid << 4) + i;
        int cnt = rowCnt[r];
        if (!cnt) continue;
        unsigned rps = rowPS[r];
        unsigned rptr = rps & 0xFFFFu, rcomp = rps >> 16;
        const float* tz = top_z + (size_t)r * TOPK;
        const int* tj = top_idx + (size_t)r * TOPK;
        for (int k = 0; k < cnt; ++k) {
            float c = fmaxf(M - tz[k], 0.0f);
            float e = expf(-(c / OT_EPS_F));
            float wv2 = e - FLOORK;
            unsigned pos = rptr + (unsigned)k;
            unsigned j = (unsigned)tj[k];
            unsigned cps = colPS[j];
            rcsr_val[pos] = wv2;
            rcsr_cid[pos] = (unsigned short)(cps >> 16);
            unsigned inc = (j & 1u) ? 65536u : 1u;
            unsigned old = atomicAdd(&colFill[j >> 1], inc);
            unsigned prior = (old >> ((j & 1u) * 16u)) & 0xFFFFu;
            unsigned cpos = (cps & 0xFFFFu) + prior;
            ccsr_val[cpos] = wv2;
            ccsr_rid[cpos] = (unsigned short)rcomp;
        }
    }
    __syncthreads();
    // ---------- B4: init scaling tables ----------
    for (int i = tid; i < 2048; i += 256) { usm[i] = 1.0f; vsm[i] = 1.0f; }
    __syncthreads();
    if (wv != 0) return;   // single-wave loop; no barriers past here

    // ---------- D: single-wave Sinkhorn (round-13 form) ----------
    const int nr = (int)nrS, nc = (int)ncS;
    float u0 = 1.0f, v0 = 1.0f;
    float SvA = (float)nc;
    for (int it = 0; it < 30; ++it) {
        const float bgu = FLOORK * ((float)(B - nc) * v0 + SvA) + 1e-8f;
        const float u0n = AMASS * rcpf_(bgu);
        for (int e = lane; e < m; e += 64)
            arr[e] = rcsr_val[e] * vsm[rcsr_cid[e]];
        lgkm0();
        float SuP = 0.0f;
        for (int i = lane; i < nr; i += 64) {
            unsigned sc = aRowSC[i];
            unsigned st = sc & 0xFFFFu, ct = sc >> 16;
            float ss = 0.0f;
            #pragma unroll
            for (unsigned k = 0; k < 8; ++k)
                if (k < ct) ss += arr[st + k];
            if (ct > 8u)
                for (unsigned k = 8; k < ct; ++k) ss += arr[st + k];
            float u = AMASS * rcpf_(bgu + ss);
            usm[i] = u; SuP += u;
        }
        const float Su = wsum64(SuP);
        const float bgv = FLOORK * ((float)(B - nr) * u0n + Su) + 1e-8f;
        const float v0n = AMASS * rcpf_(bgv);
        lgkm0();
        for (int e = lane; e < m; e += 64)
            arr[e] = ccsr_val[e] * usm[ccsr_rid[e]];
        lgkm0();
        float SvP = 0.0f; bool moved = false;
        for (int i = lane; i < nc; i += 64) {
            unsigned sc = aColSC[i];
            unsigned st = sc & 0xFFFFu, ct = sc >> 16;
            float ss = 0.0f;
            #pragma unroll
            for (unsigned k = 0; k < 8; ++k)
                if (k < ct) ss += arr[st + k];
            if (ct > 8u)
                for (unsigned k = 8; k < ct; ++k) ss += arr[st + k];
            float vn = AMASS * rcpf_(bgv + ss);
            float vold = vsm[i];
            if (fabsf(vn - vold) > EPS_C * vold) moved = true;
            vsm[i] = vn; SvP += vn;
        }
        SvA = wsum64(SvP);
        const bool conv = (__ballot(moved) == 0ull) &&
                          (fabsf(v0n - v0) <= EPS_C * v0) &&
                          (fabsf(u0n - u0) <= EPS_C * u0);
        u0 = u0n; v0 = v0n;
        lgkm0();
        if (conv) break;
    }
    // epilogue: fill background v0, overwrite active cols
    float4* vo4 = (float4*)vout;
    const float4 fill = make_float4(v0, v0, v0, v0);
    #pragma unroll
    for (int t = 0; t < 16; ++t)
        vo4[lane + (t << 6)] = fill;
    vm0();
    for (int i = lane; i < nc; i += 64)
        vout[aColJ[i]] = vsm[i];
}

// ---------------------------------------------------------------------------
// k4_fb: list-free global Sinkhorn fallback (meta[0]==1 only). Correctness path.
// ---------------------------------------------------------------------------
__global__ __launch_bounds__(256) void k4_fb(const unsigned int* __restrict__ meta,
                                             const unsigned int* __restrict__ Mkey,
                                             const float* __restrict__ top_z,
                                             const int* __restrict__ top_idx,
                                             float* __restrict__ evals,
                                             float* __restrict__ gv,
                                             float* __restrict__ ga,
                                             float* __restrict__ gb,
                                             float* __restrict__ vout) {
    if (meta[0] == 0u) return;
    __shared__ float red[4];
    __shared__ float bc;
    const int tid = threadIdx.x, lane = tid & 63, wv = tid >> 6;
    const float M = finv(Mkey[0]);

    for (int c = tid; c < B * TOPK; c += 256) {
        float cc = fmaxf(M - top_z[c], 0.0f);
        float e = 0.0f;
        if (cc < CPRE) {
            float t = expf(-(cc / OT_EPS_F));
            if (t > FLOORK) e = t - FLOORK;
        }
        evals[c] = e;
    }
    for (int i = tid; i < B; i += 256) gv[i] = 1.0f;
    __syncthreads();

    for (int it = 0; it < 30; ++it) {
        float s = 0.0f;
        for (int i = tid; i < B; i += 256) { s += gv[i]; ga[i] = 0.0f; }
        for (int o = 1; o < 64; o <<= 1) s += __shfl_xor(s, o);
        if (lane == 0) red[wv] = s;
        __syncthreads();
        if (tid == 0) bc = red[0] + red[1] + red[2] + red[3];
        __syncthreads();
        const float bgu = FLOORK * bc + 1e-8f;
        for (int c = tid; c < B * TOPK; c += 256) {
            float a = evals[c];
            if (a > 0.0f) atomicAdd(&ga[c >> 5], a * gv[top_idx[c]]);
        }
        __syncthreads();
        float su = 0.0f;
        for (int i = tid; i < B; i += 256) { su += AMASS / (bgu + ga[i]); gb[i] = 0.0f; }
        for (int o = 1; o < 64; o <<= 1) su += __shfl_xor(su, o);
        if (lane == 0) red[wv] = su;
        __syncthreads();
        if (tid == 0) bc = red[0] + red[1] + red[2] + red[3];
        __syncthreads();
        const float bgv = FLOORK * bc + 1e-8f;
        for (int c = tid; c < B * TOPK; c += 256) {
            float a = evals[c];
            if (a > 0.0f) {
                float u = AMASS / (bgu + ga[c >> 5]);
                atomicAdd(&gb[top_idx[c]], a * u);
            }
        }
        __syncthreads();
        for (int i = tid; i < B; i += 256) gv[i] = AMASS / (bgv + gb[i]);
        __syncthreads();
    }
    for (int i = tid; i < B; i += 256) vout[i] = gv[i];
}

// ---------------------------------------------------------------------------
// k5: per row: weights = K*v (u cancels), synthetic negative, normalize,
// dot with text row.
// ---------------------------------------------------------------------------
__global__ __launch_bounds__(256) void k5_synth(const int* __restrict__ top_idx,
                                                const float* __restrict__ top_z,
                                                const unsigned int* __restrict__ Mkey,
                                                const float* __restrict__ v,
                                                const float* __restrict__ image,
                                                const float* __restrict__ text,
                                                float* __restrict__ synth_sim) {
    __shared__ float sw[TOPK];
    __shared__ int   sj[TOPK];
    __shared__ float red[4];
    __shared__ float bcast;

    const int row = blockIdx.x, tid = threadIdx.x;
    const int wid = tid >> 6, lane = tid & 63;
    const float M = finv(Mkey[0]);

    if (tid < 64) {
        float wt = 0.0f;
        if (tid < TOPK) {
            int j = top_idx[(size_t)row * TOPK + tid];
            float z = top_z[(size_t)row * TOPK + tid];
            float c = fmaxf(M - z, 0.0f);
            float K = fmaxf(expf(-(c / OT_EPS_F)), FLOORK);
            wt = K * v[j];
            sj[tid] = j;
            sw[tid] = wt;
        }
        float s = wt;
        for (int off = 32; off; off >>= 1) s += __shfl_down(s, off);
        if (tid == 0) bcast = fmaxf(s, 1e-8f);
    }
    __syncthreads();
    if (tid < TOPK) sw[tid] = sw[tid] / bcast;
    __syncthreads();

    float s0 = 0.0f, s1 = 0.0f;
    for (int t = 0; t < TOPK; ++t) {
        float wv2 = sw[t];
        const float* img = image + (size_t)sj[t] * D;
        s0 += wv2 * img[tid];
        s1 += wv2 * img[tid + 256];
    }
    float nn = s0 * s0 + s1 * s1;
    for (int off = 32; off; off >>= 1) nn += __shfl_down(nn, off);
    if (lane == 0) red[wid] = nn;
    __syncthreads();
    float norm2 = red[0] + red[1] + red[2] + red[3];
    float den = sqrtf(norm2) + 1e-8f;
    float p = (s0 / den) * text[(size_t)row * D + tid] +
              (s1 / den) * text[(size_t)row * D + tid + 256];
    __syncthreads();
    for (int off = 32; off; off >>= 1) p += __shfl_down(p, off);
    if (lane == 0) red[wid] = p;
    __syncthreads();
    if (tid == 0) synth_sim[row] = red[0] + red[1] + red[2] + red[3];
}

// ---------------------------------------------------------------------------
// k78: median of ratio via radix select, then gate + final combine.
// ---------------------------------------------------------------------------
__global__ __launch_bounds__(256) void k78_final(const float* __restrict__ ratio,
                                                 const float* __restrict__ synth_sim,
                                                 const double* __restrict__ base_acc,
                                                 float* __restrict__ out) {
    __shared__ unsigned int skey[B];
    __shared__ unsigned int histm[4 * 257 + 4];
    __shared__ unsigned int selb, selk;
    __shared__ double rs[4];
    __shared__ float rg[4];

    const int tid = threadIdx.x, wid = tid >> 6, lane = tid & 63;

    #pragma unroll
    for (int t = 0; t < 16; ++t) {
        int c = tid + (t << 8);
        skey[c] = fkey(ratio[c]);
    }
    __syncthreads();

    unsigned int prefix = 0, kneed = 2048;
    for (int r = 0; r < 4; ++r) {
        for (int i = tid; i < 4 * 257 + 4; i += 256) histm[i] = 0;
        __syncthreads();
        const int shift = 24 - 8 * r;
        unsigned int cb = 0xFFFFFFFFu, cc = 0;
        #pragma unroll
        for (int t = 0; t < 16; ++t) {
            unsigned int kx = skey[tid + (t << 8)];
            bool part = (r == 0) || ((kx >> (32 - 8 * r)) == prefix);
            if (part) {
                unsigned int bin = (kx >> shift) & 255u;
                if (bin == cb) ++cc;
                else {
                    if (cc) atomicAdd(&histm[wid * 257 + cb], cc);
                    cb = bin; cc = 1;
                }
            }
        }
        if (cc) atomicAdd(&histm[wid * 257 + cb], cc);
        __syncthreads();
        unsigned int h = histm[tid] + histm[257 + tid] + histm[514 + tid] + histm[771 + tid];
        unsigned int s = h;
        for (int off = 1; off < 64; off <<= 1) {
            unsigned int o = __shfl_down(s, off);
            if (lane + off < 64) s += o;
        }
        if (lane == 0) histm[1028 + wid] = s;
        __syncthreads();
        unsigned int coarse = 0;
        for (int w = wid + 1; w < 4; ++w) coarse += histm[1028 + w];
        unsigned int incl = s + coarse, strict = incl - h;
        if (strict < kneed && kneed <= incl) { selb = (unsigned int)tid; selk = kneed - strict; }
        __syncthreads();
        prefix = (prefix << 8) | selb;
        kneed = selk;
        __syncthreads();
    }
    const unsigned int KA = prefix;
    const unsigned int g = 2048u - kneed;

    unsigned int ec = 0, mb = 0;
    #pragma unroll
    for (int t = 0; t < 16; ++t) {
        unsigned int kx = skey[tid + (t << 8)];
        if (kx == KA) ++ec;
        else if (kx < KA && kx > mb) mb = kx;
    }
    for (int off = 1; off < 64; off <<= 1) {
        ec += __shfl_xor(ec, off);
        unsigned int o = __shfl_xor(mb, off);
        mb = (o > mb) ? o : mb;
    }
    __syncthreads();
    if (lane == 0) { histm[wid] = ec; histm[8 + wid] = mb; }
    __syncthreads();
    unsigned int E  = histm[0] + histm[1] + histm[2] + histm[3];
    unsigned int MB = max(max(histm[8], histm[9]), max(histm[10], histm[11]));
    unsigned int KB = (g + E >= 2049u) ? KA : MB;
    const float scale = 0.5f * (finv(KA) + finv(KB));

    double lsd = 0.0; float gs = 0.0f;
    #pragma unroll
    for (int t = 0; t < 16; ++t) {
        float sl = scale * synth_sim[tid + (t << 8)];
        if (sl > -0.05f) { gs += 1.0f; lsd += (double)softplusf(sl); }
    }
    for (int off = 1; off < 64; off <<= 1) {
        lsd += __shfl_xor(lsd, off);
        gs  += __shfl_xor(gs, off);
    }
    if (lane == 0) { rs[wid] = lsd; rg[wid] = gs; }
    __syncthreads();
    if (tid == 0) {
        double L = rs[0] + rs[1] + rs[2] + rs[3];
        float  G = rg[0] + rg[1] + rg[2] + rg[3];
        double base = base_acc[0] / ((double)B * (double)B);
        double synth = (G > 0.0f) ? (L / ((double)G + 1e-8)) : 0.0;
        out[0] = (float)(base + 0.5 * synth);
    }
}

extern "C" void kernel_launch(void* const* d_in, const int* in_sizes, int n_in,
                              void* d_out, int out_size, void* d_ws, size_t ws_size,
                              hipStream_t stream) {
    const float* logits = (const float*)d_in[0];
    const float* text   = (const float*)d_in[1];
    const float* image  = (const float*)d_in[2];
    const float* bias   = (const float*)d_in[3];

    char* ws = (char*)d_ws;
    double*       base_acc = (double*)(ws + 0);
    unsigned int* mcount   = (unsigned int*)(ws + 8);
    unsigned int* Mkey     = (unsigned int*)(ws + 12);
    unsigned int* meta     = (unsigned int*)(ws + 16);
    unsigned int* flags    = (unsigned int*)(ws + 64);            // 16 KB
    float*        rowsum   = (float*)(ws + 64 + 16384);
    unsigned int* rowmaxk  = (unsigned int*)(rowsum + B);
    float*        v        = (float*)(rowmaxk + B);
    float*        sim      = v + B;
    float*        ratio    = sim + B;
    float*        gv       = ratio + B;
    float*        ga       = gv + B;
    float*        gb       = ga + B;
    int*          top_idx  = (int*)(gb + B);
    float*        top_z    = (float*)(top_idx + (size_t)B * TOPK);
    float*        evals    = (float*)(top_z + (size_t)B * TOPK);

    // zero: header + flags (k1_fallback gating)
    hipMemsetAsync(ws, 0, 64 + 16384, stream);

    k1_row     <<<B / 4, 256, 0, stream>>>(logits, text, image, bias, rowsum, rowmaxk,
                                           top_idx, top_z, ratio, flags);
    k1_fallback<<<B, 256, 0, stream>>>(logits, bias, flags, top_idx, top_z);
    kmid       <<<1, 256, 0, stream>>>(rowsum, rowmaxk, top_z, top_idx, Mkey, base_acc,
                                       mcount, meta, v);
    k4_fb      <<<1, 256, 0, stream>>>(meta, Mkey, top_z, top_idx, evals, gv, ga, gb, v);
    k5_synth   <<<B, 256, 0, stream>>>(top_idx, top_z, Mkey, v, image, text, sim);
    k78_final  <<<1, 256, 0, stream>>>(ratio, sim, base_acc, (float*)d_out);
}

// Round 16
// 197.889 us; speedup vs baseline: 1.8253x; 1.8253x over previous
//
#include <hip/hip_runtime.h>
#include <math.h>

#define B 4096
#define D 512
#define TOPK 32
#define MCAP 2048

constexpr float OT_EPS_F = 0.05f;
constexpr float FLOORK   = 1e-12f;
constexpr float AMASS    = 1.0f / 4096.0f;   // exact 2^-12
constexpr float TAU      = 1.8f;             // k1 candidate prefilter threshold
constexpr float EPS_L    = 1e-4f;            // loop convergence tolerance (bounded drift)
constexpr float CPRE     = 1.45f;            // conservative cost prefilter (fallback path)
constexpr float CTHR     = 1.3815510f;       // analytic: e>1e-12 <=> c < 0.05*ln(1e12)

// fast softplus via HW transcendentals (v_exp_f32 / v_log_f32), ~1e-7 abs err
__device__ __forceinline__ float softplusf(float x) {
    return fmaxf(x, 0.0f) + __logf(1.0f + __expf(-fabsf(x)));
}
__device__ __forceinline__ unsigned int fkey(float f) {
    unsigned int x = __float_as_uint(f);
    return x ^ ((x & 0x80000000u) ? 0xFFFFFFFFu : 0x80000000u);
}
__device__ __forceinline__ float finv(unsigned int k) {
    unsigned int x = (k & 0x80000000u) ? (k ^ 0x80000000u) : ~k;
    return __uint_as_float(x);
}
__device__ __forceinline__ float rcpf_(float x) { return __builtin_amdgcn_rcpf(x); }
__device__ __forceinline__ void lgkm0() {
    asm volatile("s_waitcnt lgkmcnt(0)" ::: "memory");
    __builtin_amdgcn_sched_barrier(0);
}
#define DPPADD(x, ctrl) ((x) + __int_as_float(__builtin_amdgcn_update_dpp(0, __float_as_int(x), (ctrl), 0xf, 0xf, false)))
__device__ __forceinline__ float wsum64(float x) {
    x = DPPADD(x, 0x111);
    x = DPPADD(x, 0x112);
    x = DPPADD(x, 0x114);
    x = DPPADD(x, 0x118);
    x = DPPADD(x, 0x142);
    x = DPPADD(x, 0x143);
    return __int_as_float(__builtin_amdgcn_readlane(__float_as_int(x), 63));
}

// ---------------------------------------------------------------------------
// k1: wave-per-row (4 rows / 256-block). HW-transcendental softplus, ballot
// top-32, VALUE-DESCENDING emission (LDS stage + 32-way rank sort) so kmid's
// prefix property holds by construction.
// ---------------------------------------------------------------------------
__global__ __launch_bounds__(256) void k1_row(const float* __restrict__ logits,
                                              const float* __restrict__ text,
                                              const float* __restrict__ image,
                                              const float* __restrict__ bias_p,
                                              float* __restrict__ rowsum,
                                              unsigned int* __restrict__ rowmaxk,
                                              int* __restrict__ top_idx,
                                              float* __restrict__ top_z,
                                              float* __restrict__ ratio,
                                              unsigned int* __restrict__ flags) {
    __shared__ unsigned int candk[4][128];
    __shared__ unsigned int candi[4][128];
    __shared__ unsigned int wcnt[4];
    __shared__ unsigned int skk[4][32];
    __shared__ unsigned int ski[4][32];

    const int tid = threadIdx.x, w = tid >> 6, lane = tid & 63;
    const int row = (blockIdx.x << 2) + w;
    const float bias = bias_p[0];
    const float* lr = logits + (size_t)row * B;
    const float4* lr4 = (const float4*)lr;

    if (lane == 0) wcnt[w] = 0;
    candk[w][lane] = 0; candk[w][lane + 64] = 0;

    float lsum = 0.0f, lmax = -INFINITY;
    bool ovf = false;

// softplus(-z) == softplus(z) - z exactly (same fp path in our formula)
#define K1ELEM(ZV, CC) do {                                                   \
        float z_ = (ZV) + bias;                                               \
        bool dg_ = ((CC) == row);                                             \
        float sp_ = softplusf(z_);                                            \
        lsum += dg_ ? (sp_ - z_) : sp_;                                       \
        float zm_ = dg_ ? -INFINITY : z_;                                     \
        lmax = fmaxf(lmax, zm_);                                              \
        if (zm_ > TAU) {                                                      \
            unsigned int p_ = atomicAdd(&wcnt[w], 1u);                        \
            if (p_ < 128u) { candk[w][p_] = __float_as_uint(z_);              \
                             candi[w][p_] = (unsigned int)(CC); }             \
            else ovf = true;                                                  \
        } } while (0)

    #pragma unroll
    for (int t = 0; t < 16; ++t) {
        float4 z4 = lr4[lane + (t << 6)];
        int cb = (lane << 2) + (t << 8);
        K1ELEM(z4.x, cb);
        K1ELEM(z4.y, cb + 1);
        K1ELEM(z4.z, cb + 2);
        K1ELEM(z4.w, cb + 3);
    }
#undef K1ELEM
    __syncthreads();

    for (int o = 1; o < 64; o <<= 1) {
        lsum += __shfl_xor(lsum, o);
        lmax = fmaxf(lmax, __shfl_xor(lmax, o));
    }
    if (lane == 0) { rowsum[row] = lsum; rowmaxk[row] = fkey(lmax); }

    const unsigned int n = wcnt[w];
    bool fb = (n < (unsigned)TOPK) || (n > 128u) || (__ballot(ovf) != 0ull);

    const unsigned int c0k = candk[w][lane], c1k = candk[w][lane + 64];
    const unsigned int i0  = candi[w][lane], i1  = candi[w][lane + 64];

    if (!fb) {
        // ballot binary search for rank-32 key (raw positive-float bits)
        unsigned int K = 0u;
        for (int b = 31; b >= 0; --b) {
            unsigned int tr = K | (1u << b);
            int cnt = __popcll(__ballot(c0k >= tr)) + __popcll(__ballot(c1k >= tr));
            if (cnt >= TOPK) K = tr;
        }
        unsigned long long m0g = __ballot(c0k > K), m1g = __ballot(c1k > K);
        unsigned long long m0e = __ballot(c0k == K), m1e = __ballot(c1k == K);
        int cnt_gt = __popcll(m0g) + __popcll(m1g);
        int kneed  = TOPK - cnt_gt;
        int eqc    = __popcll(m0e) + __popcll(m1e);
        if (eqc != kneed) {
            fb = true;   // boundary ties -> exact fallback
        } else {
            unsigned long long lmlt = (1ull << lane) - 1ull;
            // stage into per-wave LDS (slot-ranked), then value-sort emit
            int r0 = __popcll(m0g & lmlt);
            if (c0k > K) { skk[w][r0] = c0k; ski[w][r0] = i0; }
            int r1 = __popcll(m0g) + __popcll(m1g & lmlt);
            if (c1k > K) { skk[w][r1] = c1k; ski[w][r1] = i1; }
            int e0 = cnt_gt + __popcll(m0e & lmlt);
            if (c0k == K) { skk[w][e0] = c0k; ski[w][e0] = i0; }
            int e1 = cnt_gt + __popcll(m0e) + __popcll(m1e & lmlt);
            if (c1k == K) { skk[w][e1] = c1k; ski[w][e1] = i1; }
            lgkm0();   // in-wave LDS ordering
            if (lane < 32) {
                unsigned int my = skk[w][lane], mi = ski[w][lane];
                int rk = 0;
                #pragma unroll
                for (int k = 0; k < 32; ++k) {
                    unsigned int ok = skk[w][k];
                    rk += (int)((ok > my) || (ok == my && k < lane));
                }
                size_t rb = (size_t)row * TOPK;
                top_idx[rb + rk] = (int)mi;
                top_z [rb + rk] = __uint_as_float(my);
            }
        }
    }
    if (fb && lane == 0) flags[row] = 1u;

    // ---- fused ratio sample ----
    unsigned int hh = (unsigned int)row * 2654435761u;
    int j = (int)(((unsigned int)row + 1u + (hh % 4095u)) & 4095u);   // j != row
    const float4* tr4 = (const float4*)(text + (size_t)row * D);
    const float4* ir4 = (const float4*)(image + (size_t)j * D);
    float4 a0 = tr4[lane], b0 = ir4[lane];
    float4 a1 = tr4[lane + 64], b1 = ir4[lane + 64];
    float s3 = a0.x * b0.x + a0.y * b0.y + a0.z * b0.z + a0.w * b0.w
             + a1.x * b1.x + a1.y * b1.y + a1.z * b1.z + a1.w * b1.w;
    for (int o = 1; o < 64; o <<= 1) s3 += __shfl_xor(s3, o);
    if (lane == 0) ratio[row] = lr[j] / (s3 + 1e-8f);
}

// ---------------------------------------------------------------------------
// k1f: exact fallback for flagged rows (LDS radix select) + final value sort.
// Normally no-op.
// ---------------------------------------------------------------------------
__global__ __launch_bounds__(256) void k1_fallback(const float* __restrict__ logits,
                                                   const float* __restrict__ bias_p,
                                                   const unsigned int* __restrict__ flags,
                                                   int* __restrict__ top_idx,
                                                   float* __restrict__ top_z) {
    const int row = blockIdx.x;
    if (flags[row] == 0u) return;

    __shared__ unsigned int skey[B];
    __shared__ unsigned int histm[4 * 257 + 4];
    __shared__ unsigned int selb, selk;
    __shared__ int cnt_gt, cnt_eq;
    __shared__ int eqi[64];
    __shared__ unsigned int sk2[32], si2[32];

    const int tid = threadIdx.x, wid = tid >> 6, lane = tid & 63;
    const float bias = bias_p[0];
    const float* lr = logits + (size_t)row * B;

    #pragma unroll
    for (int t = 0; t < 16; ++t) {
        int c = tid + (t << 8);
        float z = lr[c] + bias;
        skey[c] = fkey((c == row) ? -INFINITY : z);
    }
    if (tid == 0) { cnt_gt = 0; cnt_eq = 0; }
    __syncthreads();

    unsigned int prefix = 0, kneed = TOPK;
    for (int r = 0; r < 4; ++r) {
        for (int i = tid; i < 4 * 257 + 4; i += 256) histm[i] = 0;
        __syncthreads();
        const int shift = 24 - 8 * r;
        #pragma unroll
        for (int t = 0; t < 16; ++t) {
            int c = tid + (t << 8);
            unsigned int kx = skey[c];
            bool part = (r == 0) || ((kx >> (32 - 8 * r)) == prefix);
            if (part) atomicAdd(&histm[wid * 257 + ((kx >> shift) & 255u)], 1u);
        }
        __syncthreads();
        unsigned int h = histm[tid] + histm[257 + tid] + histm[514 + tid] + histm[771 + tid];
        unsigned int s = h;
        for (int off = 1; off < 64; off <<= 1) {
            unsigned int o = __shfl_down(s, off);
            if (lane + off < 64) s += o;
        }
        if (lane == 0) histm[1028 + wid] = s;
        __syncthreads();
        unsigned int coarse = 0;
        for (int ww = wid + 1; ww < 4; ++ww) coarse += histm[1028 + ww];
        unsigned int incl = s + coarse, strict = incl - h;
        if (strict < kneed && kneed <= incl) { selb = (unsigned int)tid; selk = kneed - strict; }
        __syncthreads();
        prefix = (prefix << 8) | selb;
        kneed = selk;
        __syncthreads();
    }
    const unsigned int K32 = prefix;

    #pragma unroll
    for (int t = 0; t < 16; ++t) {
        int c = tid + (t << 8);
        unsigned int kx = skey[c];
        if (kx > K32) {
            int p = atomicAdd(&cnt_gt, 1);
            top_idx[(size_t)row * TOPK + p] = c;
            top_z [(size_t)row * TOPK + p] = finv(kx);
        } else if (kx == K32) {
            int p = atomicAdd(&cnt_eq, 1);
            if (p < 64) eqi[p] = c;
        }
    }
    __syncthreads();
    if (tid == 0) {
        int q = (int)kneed, base = cnt_gt, E = cnt_eq;
        float zv = finv(K32);
        if (E <= 64) {
            for (int s2 = 0; s2 < q; ++s2) {
                int best = 0x7FFFFFFF, bp = 0;
                for (int e = 0; e < E; ++e) { int ix = eqi[e]; if (ix < best) { best = ix; bp = e; } }
                eqi[bp] = 0x7FFFFFFF;
                top_idx[(size_t)row * TOPK + base + s2] = best;
                top_z [(size_t)row * TOPK + base + s2] = zv;
            }
        } else {
            int taken = 0;
            for (int c = 0; c < B && taken < q; ++c)
                if (skey[c] == K32) {
                    top_idx[(size_t)row * TOPK + taken + base] = c;
                    top_z [(size_t)row * TOPK + taken + base] = zv;
                    ++taken;
                }
        }
    }
    __syncthreads();   // drains global writes before re-read
    if (tid < 32) {
        sk2[tid] = fkey(top_z[(size_t)row * TOPK + tid]);
        si2[tid] = (unsigned int)top_idx[(size_t)row * TOPK + tid];
    }
    __syncthreads();
    if (tid < 32) {
        unsigned int my = sk2[tid], mi = si2[tid];
        int rk = 0;
        #pragma unroll
        for (int k = 0; k < 32; ++k) {
            unsigned int ok = sk2[k];
            rk += (int)((ok > my) || (ok == my && k < tid));
        }
        top_idx[(size_t)row * TOPK + rk] = (int)mi;
        top_z [(size_t)row * TOPK + rk] = finv(my);
    }
}

// ---------------------------------------------------------------------------
// kmid: fused reduce + CSR build + 4-wave DIRECT-GATHER Sinkhorn with only
// 2 barriers/iter (no scatter intermediate; reductions folded into the two
// phase barriers). m <= 2048. Relaxed loop tolerance EPS_L (bounded drift).
// ---------------------------------------------------------------------------
__global__ __launch_bounds__(256) void kmid(const float* __restrict__ rowsum,
                                            const unsigned int* __restrict__ rowmaxk,
                                            const float* __restrict__ top_z,
                                            const int* __restrict__ top_idx,
                                            unsigned int* __restrict__ Mkey_g,
                                            double* __restrict__ base_acc_g,
                                            unsigned int* __restrict__ mcount_g,
                                            unsigned int* __restrict__ meta_g,
                                            float* __restrict__ vout) {
    __shared__ __align__(16) unsigned char SB[94208];
    float*  rcsr_val = (float*)(SB + 0);
    float*  ccsr_val = (float*)(SB + 8192);
    float*  usm      = (float*)(SB + 24576);
    float*  vsm      = (float*)(SB + 32768);
    unsigned* aRowSC = (unsigned*)(SB + 40960);
    unsigned* aColSC = (unsigned*)(SB + 49152);
    unsigned short* rcsr_cid = (unsigned short*)(SB + 57344);
    unsigned short* ccsr_rid = (unsigned short*)(SB + 61440);
    unsigned short* aColJ    = (unsigned short*)(SB + 65536);
    unsigned* colPS  = (unsigned*)(SB + 69632);
    unsigned short* rowCnt = (unsigned short*)(SB + 86016);
    unsigned* colCnt  = (unsigned*)(SB + 0);                // build overlay (rcsr_val+ccsr_val)
    unsigned* rowPS   = (unsigned*)(SB + 24576);            // build overlay (usm+vsm)
    unsigned* colFill = (unsigned*)(SB + 16384);            // build overlay

    __shared__ double sdbl[4];
    __shared__ unsigned smax4[4];
    __shared__ float sMf;
    __shared__ unsigned mTot;
    __shared__ unsigned wq[4];
    __shared__ unsigned nrS, ncS;
    __shared__ float redA[4], redB[4];
    __shared__ unsigned mvf[4];

    const int tid = threadIdx.x, lane = tid & 63, wv = tid >> 6;

    // ---------- A: reduce ----------
    {
        double s = 0.0; unsigned mk = 0u;
        #pragma unroll
        for (int t = 0; t < 16; ++t) {
            int i = tid + (t << 8);
            s += (double)rowsum[i];
            unsigned k = rowmaxk[i];
            mk = (k > mk) ? k : mk;
        }
        for (int o = 1; o < 64; o <<= 1) {
            s += __shfl_xor(s, o);
            unsigned om = __shfl_xor(mk, o);
            mk = (om > mk) ? om : mk;
        }
        if (lane == 0) { sdbl[wv] = s; smax4[wv] = mk; }
        if (tid == 0) mTot = 0u;
    }
    __syncthreads();
    if (tid == 0) {
        *base_acc_g = sdbl[0] + sdbl[1] + sdbl[2] + sdbl[3];
        unsigned m2 = max(max(smax4[0], smax4[1]), max(smax4[2], smax4[3]));
        *Mkey_g = m2;
        sMf = finv(m2);
    }
    __syncthreads();
    const float M = sMf;
    const float zthr = M - CTHR;

    // ---------- B1: vectorized survivor count + col histogram ----------
    for (int i = tid; i < 4096; i += 256) colCnt[i] = 0u;
    __syncthreads();
    {
        unsigned myTot = 0;
        for (int i = 0; i < 16; ++i) {
            int r = (tid << 4) + i;
            const float4* tz4 = (const float4*)(top_z + (size_t)r * TOPK);
            int cnt = 0;
            #pragma unroll
            for (int q = 0; q < 8; ++q) {
                float4 t = tz4[q];
                cnt += (t.x > zthr) + (t.y > zthr) + (t.z > zthr) + (t.w > zthr);
            }
            rowCnt[r] = (unsigned short)cnt;
            myTot += (unsigned)cnt;
            const int* tj = top_idx + (size_t)r * TOPK;
            for (int k = 0; k < cnt; ++k)
                atomicAdd(&colCnt[(unsigned)tj[k]], 1u);
        }
        atomicAdd(&mTot, myTot);
    }
    __syncthreads();
    const int m = (int)mTot;
    if (tid == 0) { mcount_g[0] = (unsigned)m; meta_g[0] = (m > MCAP) ? 1u : 0u; }
    if (m > MCAP) return;

    // ---------- B2a: row scan ----------
    {
        unsigned pre[16]; unsigned tsum = 0;
        #pragma unroll
        for (int i = 0; i < 16; ++i) {
            unsigned c2 = rowCnt[(tid << 4) + i];
            unsigned val = c2 | ((c2 ? 1u : 0u) << 16);
            pre[i] = tsum; tsum += val;
        }
        unsigned sc = tsum;
        for (int o = 1; o < 64; o <<= 1) {
            unsigned n2 = __shfl_up(sc, o);
            if (lane >= o) sc += n2;
        }
        if (lane == 63) wq[wv] = sc;
        __syncthreads();
        unsigned woff = 0;
        for (int w2 = 0; w2 < wv; ++w2) woff += wq[w2];
        unsigned base0 = woff + sc - tsum;
        #pragma unroll
        for (int i = 0; i < 16; ++i) {
            int r = (tid << 4) + i;
            unsigned pfx = base0 + pre[i];
            rowPS[r] = pfx;
            unsigned c2 = rowCnt[r];
            if (c2) aRowSC[pfx >> 16] = (pfx & 0xFFFFu) | (c2 << 16);
        }
        if (tid == 255) nrS = (base0 + tsum) >> 16;
    }
    __syncthreads();
    // ---------- B2b: col scan ----------
    {
        unsigned pre[16]; unsigned tsum = 0;
        #pragma unroll
        for (int i = 0; i < 16; ++i) {
            unsigned c2 = colCnt[(tid << 4) + i];
            unsigned val = c2 | ((c2 ? 1u : 0u) << 16);
            pre[i] = tsum; tsum += val;
        }
        unsigned sc = tsum;
        for (int o = 1; o < 64; o <<= 1) {
            unsigned n2 = __shfl_up(sc, o);
            if (lane >= o) sc += n2;
        }
        if (lane == 63) wq[wv] = sc;
        __syncthreads();
        unsigned woff = 0;
        for (int w2 = 0; w2 < wv; ++w2) woff += wq[w2];
        unsigned base0 = woff + sc - tsum;
        #pragma unroll
        for (int i = 0; i < 16; ++i) {
            int j = (tid << 4) + i;
            unsigned pfx = base0 + pre[i];
            colPS[j] = pfx;
            unsigned c2 = colCnt[j];
            if (c2) {
                unsigned cc = pfx >> 16;
                aColSC[cc] = (pfx & 0xFFFFu) | (c2 << 16);
                aColJ[cc] = (unsigned short)j;
            }
        }
        if (tid == 255) ncS = (base0 + tsum) >> 16;
    }
    __syncthreads();
    {   // max col count guard (cnt must be sane; conservative 64)
        unsigned mcc = 0;
        #pragma unroll
        for (int i = 0; i < 16; ++i) mcc = max(mcc, colCnt[(tid << 4) + i]);
        for (int o = 1; o < 64; o <<= 1) { unsigned t2 = __shfl_xor(mcc, o); mcc = max(mcc, t2); }
        if (lane == 0) smax4[wv] = mcc;
    }
    __syncthreads();
    {
        unsigned mx = max(max(smax4[0], smax4[1]), max(smax4[2], smax4[3]));
        if (tid == 0 && mx > 64u) meta_g[0] = 1u;
        if (mx > 64u) return;   // uniform
    }

    // ---------- B3: fill CSR ----------
    for (int i = tid; i < 2048; i += 256) colFill[i] = 0u;
    __syncthreads();
    for (int i = 0; i < 16; ++i) {
        int r = (tid << 4) + i;
        int cnt = rowCnt[r];
        if (!cnt) continue;
        unsigned rps = rowPS[r];
        unsigned rptr = rps & 0xFFFFu, rcomp = rps >> 16;
        const float* tz = top_z + (size_t)r * TOPK;
        const int* tj = top_idx + (size_t)r * TOPK;
        for (int k = 0; k < cnt; ++k) {
            float c = fmaxf(M - tz[k], 0.0f);
            float e = expf(-(c / OT_EPS_F));
            float wv2 = e - FLOORK;
            unsigned pos = rptr + (unsigned)k;
            unsigned j = (unsigned)tj[k];
            unsigned cps = colPS[j];
            rcsr_val[pos] = wv2;
            rcsr_cid[pos] = (unsigned short)(cps >> 16);
            unsigned inc = (j & 1u) ? 65536u : 1u;
            unsigned old = atomicAdd(&colFill[j >> 1], inc);
            unsigned prior = (old >> ((j & 1u) * 16u)) & 0xFFFFu;
            unsigned cpos = (cps & 0xFFFFu) + prior;
            ccsr_val[cpos] = wv2;
            ccsr_rid[cpos] = (unsigned short)rcomp;
        }
    }
    __syncthreads();
    // ---------- B4: init scaling tables (frees rowPS overlay of usm/vsm) ----------
    for (int i = tid; i < 2048; i += 256) { usm[i] = 1.0f; vsm[i] = 1.0f; }
    __syncthreads();

    // ---------- D: 4-wave direct-gather Sinkhorn, 2 barriers/iter ----------
    const int nr = (int)nrS, nc = (int)ncS;
    float u0 = 1.0f, v0 = 1.0f;
    float SvA = (float)nc;
    for (int it = 0; it < 30; ++it) {
        const float bgu = FLOORK * ((float)(B - nc) * v0 + SvA) + 1e-8f;
        const float u0n = AMASS * rcpf_(bgu);
        float SuP = 0.0f;
        for (int i = tid; i < nr; i += 256) {
            unsigned sc = aRowSC[i];
            unsigned st = sc & 0xFFFFu, ct = sc >> 16;
            float ss = 0.0f;
            for (unsigned k = 0; k < ct; ++k)
                ss += rcsr_val[st + k] * vsm[rcsr_cid[st + k]];
            float u = AMASS * rcpf_(bgu + ss);
            usm[i] = u;
            SuP += u;
        }
        SuP = wsum64(SuP);
        if (lane == 0) redA[wv] = SuP;
        __syncthreads();                                   // (1) usm + redA ready
        const float Su = redA[0] + redA[1] + redA[2] + redA[3];
        const float bgv = FLOORK * ((float)(B - nr) * u0n + Su) + 1e-8f;
        const float v0n = AMASS * rcpf_(bgv);
        float SvP = 0.0f; bool moved = false;
        for (int i = tid; i < nc; i += 256) {
            unsigned sc = aColSC[i];
            unsigned st = sc & 0xFFFFu, ct = sc >> 16;
            float ss = 0.0f;
            for (unsigned k = 0; k < ct; ++k)
                ss += ccsr_val[st + k] * usm[ccsr_rid[st + k]];
            float vn = AMASS * rcpf_(bgv + ss);
            float vold = vsm[i];
            if (fabsf(vn - vold) > EPS_L * vold) moved = true;
            vsm[i] = vn;
            SvP += vn;
        }
        SvP = wsum64(SvP);
        if (lane == 0) { redB[wv] = SvP; mvf[wv] = (__ballot(moved) != 0ull) ? 1u : 0u; }
        __syncthreads();                                   // (2) vsm + redB + mvf ready
        SvA = redB[0] + redB[1] + redB[2] + redB[3];
        const bool conv = ((mvf[0] | mvf[1] | mvf[2] | mvf[3]) == 0u) &&
                          (fabsf(v0n - v0) <= EPS_L * v0) &&
                          (fabsf(u0n - u0) <= EPS_L * u0);
        u0 = u0n; v0 = v0n;
        if (conv) break;   // uniform (all threads see same mvf/u0/v0)
    }

    // ---------- epilogue: fill background v0, overwrite active cols ----------
    {
        float4* vo4 = (float4*)vout;
        const float4 fill = make_float4(v0, v0, v0, v0);
        for (int t2 = tid; t2 < 1024; t2 += 256) vo4[t2] = fill;
        __syncthreads();   // all fill stores complete before scatter
        for (int i = tid; i < nc; i += 256)
            vout[aColJ[i]] = vsm[i];
    }
}

// ---------------------------------------------------------------------------
// k4_fb: list-free global Sinkhorn fallback (meta[0]==1 only). Correctness path.
// ---------------------------------------------------------------------------
__global__ __launch_bounds__(256) void k4_fb(const unsigned int* __restrict__ meta,
                                             const unsigned int* __restrict__ Mkey,
                                             const float* __restrict__ top_z,
                                             const int* __restrict__ top_idx,
                                             float* __restrict__ evals,
                                             float* __restrict__ gv,
                                             float* __restrict__ ga,
                                             float* __restrict__ gb,
                                             float* __restrict__ vout) {
    if (meta[0] == 0u) return;
    __shared__ float red[4];
    __shared__ float bc;
    const int tid = threadIdx.x, lane = tid & 63, wv = tid >> 6;
    const float M = finv(Mkey[0]);

    for (int c = tid; c < B * TOPK; c += 256) {
        float cc = fmaxf(M - top_z[c], 0.0f);
        float e = 0.0f;
        if (cc < CPRE) {
            float t = expf(-(cc / OT_EPS_F));
            if (t > FLOORK) e = t - FLOORK;
        }
        evals[c] = e;
    }
    for (int i = tid; i < B; i += 256) gv[i] = 1.0f;
    __syncthreads();

    for (int it = 0; it < 30; ++it) {
        float s = 0.0f;
        for (int i = tid; i < B; i += 256) { s += gv[i]; ga[i] = 0.0f; }
        for (int o = 1; o < 64; o <<= 1) s += __shfl_xor(s, o);
        if (lane == 0) red[wv] = s;
        __syncthreads();
        if (tid == 0) bc = red[0] + red[1] + red[2] + red[3];
        __syncthreads();
        const float bgu = FLOORK * bc + 1e-8f;
        for (int c = tid; c < B * TOPK; c += 256) {
            float a = evals[c];
            if (a > 0.0f) atomicAdd(&ga[c >> 5], a * gv[top_idx[c]]);
        }
        __syncthreads();
        float su = 0.0f;
        for (int i = tid; i < B; i += 256) { su += AMASS / (bgu + ga[i]); gb[i] = 0.0f; }
        for (int o = 1; o < 64; o <<= 1) su += __shfl_xor(su, o);
        if (lane == 0) red[wv] = su;
        __syncthreads();
        if (tid == 0) bc = red[0] + red[1] + red[2] + red[3];
        __syncthreads();
        const float bgv = FLOORK * bc + 1e-8f;
        for (int c = tid; c < B * TOPK; c += 256) {
            float a = evals[c];
            if (a > 0.0f) {
                float u = AMASS / (bgu + ga[c >> 5]);
                atomicAdd(&gb[top_idx[c]], a * u);
            }
        }
        __syncthreads();
        for (int i = tid; i < B; i += 256) gv[i] = AMASS / (bgv + gb[i]);
        __syncthreads();
    }
    for (int i = tid; i < B; i += 256) vout[i] = gv[i];
}

// ---------------------------------------------------------------------------
// k5: per row: weights = K*v (u cancels), synthetic negative, normalize,
// dot with text row.
// ---------------------------------------------------------------------------
__global__ __launch_bounds__(256) void k5_synth(const int* __restrict__ top_idx,
                                                const float* __restrict__ top_z,
                                                const unsigned int* __restrict__ Mkey,
                                                const float* __restrict__ v,
                                                const float* __restrict__ image,
                                                const float* __restrict__ text,
                                                float* __restrict__ synth_sim) {
    __shared__ float sw[TOPK];
    __shared__ int   sj[TOPK];
    __shared__ float red[4];
    __shared__ float bcast;

    const int row = blockIdx.x, tid = threadIdx.x;
    const int wid = tid >> 6, lane = tid & 63;
    const float M = finv(Mkey[0]);

    if (tid < 64) {
        float wt = 0.0f;
        if (tid < TOPK) {
            int j = top_idx[(size_t)row * TOPK + tid];
            float z = top_z[(size_t)row * TOPK + tid];
            float c = fmaxf(M - z, 0.0f);
            float K = fmaxf(expf(-(c / OT_EPS_F)), FLOORK);
            wt = K * v[j];
            sj[tid] = j;
            sw[tid] = wt;
        }
        float s = wt;
        for (int off = 32; off; off >>= 1) s += __shfl_down(s, off);
        if (tid == 0) bcast = fmaxf(s, 1e-8f);
    }
    __syncthreads();
    if (tid < TOPK) sw[tid] = sw[tid] / bcast;
    __syncthreads();

    float s0 = 0.0f, s1 = 0.0f;
    for (int t = 0; t < TOPK; ++t) {
        float wv2 = sw[t];
        const float* img = image + (size_t)sj[t] * D;
        s0 += wv2 * img[tid];
        s1 += wv2 * img[tid + 256];
    }
    float nn = s0 * s0 + s1 * s1;
    for (int off = 32; off; off >>= 1) nn += __shfl_down(nn, off);
    if (lane == 0) red[wid] = nn;
    __syncthreads();
    float norm2 = red[0] + red[1] + red[2] + red[3];
    float den = sqrtf(norm2) + 1e-8f;
    float p = (s0 / den) * text[(size_t)row * D + tid] +
              (s1 / den) * text[(size_t)row * D + tid + 256];
    __syncthreads();
    for (int off = 32; off; off >>= 1) p += __shfl_down(p, off);
    if (lane == 0) red[wid] = p;
    __syncthreads();
    if (tid == 0) synth_sim[row] = red[0] + red[1] + red[2] + red[3];
}

// ---------------------------------------------------------------------------
// k78: median of ratio via radix select, then gate + final combine.
// ---------------------------------------------------------------------------
__global__ __launch_bounds__(256) void k78_final(const float* __restrict__ ratio,
                                                 const float* __restrict__ synth_sim,
                                                 const double* __restrict__ base_acc,
                                                 float* __restrict__ out) {
    __shared__ unsigned int skey[B];
    __shared__ unsigned int histm[4 * 257 + 4];
    __shared__ unsigned int selb, selk;
    __shared__ double rs[4];
    __shared__ float rg[4];

    const int tid = threadIdx.x, wid = tid >> 6, lane = tid & 63;

    #pragma unroll
    for (int t = 0; t < 16; ++t) {
        int c = tid + (t << 8);
        skey[c] = fkey(ratio[c]);
    }
    __syncthreads();

    unsigned int prefix = 0, kneed = 2048;
    for (int r = 0; r < 4; ++r) {
        for (int i = tid; i < 4 * 257 + 4; i += 256) histm[i] = 0;
        __syncthreads();
        const int shift = 24 - 8 * r;
        unsigned int cb = 0xFFFFFFFFu, cc = 0;
        #pragma unroll
        for (int t = 0; t < 16; ++t) {
            unsigned int kx = skey[tid + (t << 8)];
            bool part = (r == 0) || ((kx >> (32 - 8 * r)) == prefix);
            if (part) {
                unsigned int bin = (kx >> shift) & 255u;
                if (bin == cb) ++cc;
                else {
                    if (cc) atomicAdd(&histm[wid * 257 + cb], cc);
                    cb = bin; cc = 1;
                }
            }
        }
        if (cc) atomicAdd(&histm[wid * 257 + cb], cc);
        __syncthreads();
        unsigned int h = histm[tid] + histm[257 + tid] + histm[514 + tid] + histm[771 + tid];
        unsigned int s = h;
        for (int off = 1; off < 64; off <<= 1) {
            unsigned int o = __shfl_down(s, off);
            if (lane + off < 64) s += o;
        }
        if (lane == 0) histm[1028 + wid] = s;
        __syncthreads();
        unsigned int coarse = 0;
        for (int w = wid + 1; w < 4; ++w) coarse += histm[1028 + w];
        unsigned int incl = s + coarse, strict = incl - h;
        if (strict < kneed && kneed <= incl) { selb = (unsigned int)tid; selk = kneed - strict; }
        __syncthreads();
        prefix = (prefix << 8) | selb;
        kneed = selk;
        __syncthreads();
    }
    const unsigned int KA = prefix;
    const unsigned int g = 2048u - kneed;

    unsigned int ec = 0, mb = 0;
    #pragma unroll
    for (int t = 0; t < 16; ++t) {
        unsigned int kx = skey[tid + (t << 8)];
        if (kx == KA) ++ec;
        else if (kx < KA && kx > mb) mb = kx;
    }
    for (int off = 1; off < 64; off <<= 1) {
        ec += __shfl_xor(ec, off);
        unsigned int o = __shfl_xor(mb, off);
        mb = (o > mb) ? o : mb;
    }
    __syncthreads();
    if (lane == 0) { histm[wid] = ec; histm[8 + wid] = mb; }
    __syncthreads();
    unsigned int E  = histm[0] + histm[1] + histm[2] + histm[3];
    unsigned int MB = max(max(histm[8], histm[9]), max(histm[10], histm[11]));
    unsigned int KB = (g + E >= 2049u) ? KA : MB;
    const float scale = 0.5f * (finv(KA) + finv(KB));

    double lsd = 0.0; float gs = 0.0f;
    #pragma unroll
    for (int t = 0; t < 16; ++t) {
        float sl = scale * synth_sim[tid + (t << 8)];
        if (sl > -0.05f) { gs += 1.0f; lsd += (double)softplusf(sl); }
    }
    for (int off = 1; off < 64; off <<= 1) {
        lsd += __shfl_xor(lsd, off);
        gs  += __shfl_xor(gs, off);
    }
    if (lane == 0) { rs[wid] = lsd; rg[wid] = gs; }
    __syncthreads();
    if (tid == 0) {
        double L = rs[0] + rs[1] + rs[2] + rs[3];
        float  G = rg[0] + rg[1] + rg[2] + rg[3];
        double base = base_acc[0] / ((double)B * (double)B);
        double synth = (G > 0.0f) ? (L / ((double)G + 1e-8)) : 0.0;
        out[0] = (float)(base + 0.5 * synth);
    }
}

extern "C" void kernel_launch(void* const* d_in, const int* in_sizes, int n_in,
                              void* d_out, int out_size, void* d_ws, size_t ws_size,
                              hipStream_t stream) {
    const float* logits = (const float*)d_in[0];
    const float* text   = (const float*)d_in[1];
    const float* image  = (const float*)d_in[2];
    const float* bias   = (const float*)d_in[3];

    char* ws = (char*)d_ws;
    double*       base_acc = (double*)(ws + 0);
    unsigned int* mcount   = (unsigned int*)(ws + 8);
    unsigned int* Mkey     = (unsigned int*)(ws + 12);
    unsigned int* meta     = (unsigned int*)(ws + 16);
    unsigned int* flags    = (unsigned int*)(ws + 64);            // 16 KB
    float*        rowsum   = (float*)(ws + 64 + 16384);
    unsigned int* rowmaxk  = (unsigned int*)(rowsum + B);
    float*        v        = (float*)(rowmaxk + B);
    float*        sim      = v + B;
    float*        ratio    = sim + B;
    float*        gv       = ratio + B;
    float*        ga       = gv + B;
    float*        gb       = ga + B;
    int*          top_idx  = (int*)(gb + B);
    float*        top_z    = (float*)(top_idx + (size_t)B * TOPK);
    float*        evals    = (float*)(top_z + (size_t)B * TOPK);

    // zero: header + flags (k1_fallback gating)
    hipMemsetAsync(ws, 0, 64 + 16384, stream);

    k1_row     <<<B / 4, 256, 0, stream>>>(logits, text, image, bias, rowsum, rowmaxk,
                                           top_idx, top_z, ratio, flags);
    k1_fallback<<<B, 256, 0, stream>>>(logits, bias, flags, top_idx, top_z);
    kmid       <<<1, 256, 0, stream>>>(rowsum, rowmaxk, top_z, top_idx, Mkey, base_acc,
                                       mcount, meta, v);
    k4_fb      <<<1, 256, 0, stream>>>(meta, Mkey, top_z, top_idx, evals, gv, ga, gb, v);
    k5_synth   <<<B, 256, 0, stream>>>(top_idx, top_z, Mkey, v, image, text, sim);
    k78_final  <<<1, 256, 0, stream>>>(ratio, sim, base_acc, (float*)d_out);
}

// Round 18
// 193.088 us; speedup vs baseline: 1.8707x; 1.0249x over previous
//
#include <hip/hip_runtime.h>
#include <math.h>

#define B 4096
#define D 512
#define TOPK 32
#define MCAP 2048

constexpr float OT_EPS_F = 0.05f;
constexpr float FLOORK   = 1e-12f;
constexpr float AMASS    = 1.0f / 4096.0f;   // exact 2^-12
constexpr float TAU      = 1.8f;             // k1 candidate prefilter threshold
constexpr float EPS_L    = 1e-4f;            // loop convergence tolerance (bounded drift)
constexpr float CPRE     = 1.45f;            // conservative cost prefilter (fallback path)
constexpr float CTHR     = 1.3815510f;       // analytic: e>1e-12 <=> c < 0.05*ln(1e12)

// fast softplus via HW transcendentals (v_exp_f32 / v_log_f32), ~1e-7 abs err
__device__ __forceinline__ float softplusf(float x) {
    return fmaxf(x, 0.0f) + __logf(1.0f + __expf(-fabsf(x)));
}
__device__ __forceinline__ unsigned int fkey(float f) {
    unsigned int x = __float_as_uint(f);
    return x ^ ((x & 0x80000000u) ? 0xFFFFFFFFu : 0x80000000u);
}
__device__ __forceinline__ float finv(unsigned int k) {
    unsigned int x = (k & 0x80000000u) ? (k ^ 0x80000000u) : ~k;
    return __uint_as_float(x);
}
__device__ __forceinline__ float rcpf_(float x) { return __builtin_amdgcn_rcpf(x); }
__device__ __forceinline__ void lgkm0() {
    asm volatile("s_waitcnt lgkmcnt(0)" ::: "memory");
    __builtin_amdgcn_sched_barrier(0);
}
#define DPPADD(x, ctrl) ((x) + __int_as_float(__builtin_amdgcn_update_dpp(0, __float_as_int(x), (ctrl), 0xf, 0xf, false)))
__device__ __forceinline__ float wsum64(float x) {
    x = DPPADD(x, 0x111);
    x = DPPADD(x, 0x112);
    x = DPPADD(x, 0x114);
    x = DPPADD(x, 0x118);
    x = DPPADD(x, 0x142);
    x = DPPADD(x, 0x143);
    return __int_as_float(__builtin_amdgcn_readlane(__float_as_int(x), 63));
}

// ---------------------------------------------------------------------------
// k1: wave-per-row (4 rows / 256-block). HW-transcendental softplus, ballot
// top-32, VALUE-DESCENDING emission (LDS stage + 32-way rank sort) so kmid's
// prefix property holds by construction.
// ---------------------------------------------------------------------------
__global__ __launch_bounds__(256) void k1_row(const float* __restrict__ logits,
                                              const float* __restrict__ text,
                                              const float* __restrict__ image,
                                              const float* __restrict__ bias_p,
                                              float* __restrict__ rowsum,
                                              unsigned int* __restrict__ rowmaxk,
                                              int* __restrict__ top_idx,
                                              float* __restrict__ top_z,
                                              float* __restrict__ ratio,
                                              unsigned int* __restrict__ flags) {
    __shared__ unsigned int candk[4][128];
    __shared__ unsigned int candi[4][128];
    __shared__ unsigned int wcnt[4];
    __shared__ unsigned int skk[4][32];
    __shared__ unsigned int ski[4][32];

    const int tid = threadIdx.x, w = tid >> 6, lane = tid & 63;
    const int row = (blockIdx.x << 2) + w;
    const float bias = bias_p[0];
    const float* lr = logits + (size_t)row * B;
    const float4* lr4 = (const float4*)lr;

    if (lane == 0) wcnt[w] = 0;
    candk[w][lane] = 0; candk[w][lane + 64] = 0;

    float lsum = 0.0f, lmax = -INFINITY;
    bool ovf = false;

#define K1ELEM(ZV, CC) do {                                                   \
        float z_ = (ZV) + bias;                                               \
        bool dg_ = ((CC) == row);                                             \
        float sp_ = softplusf(z_);                                            \
        lsum += dg_ ? (sp_ - z_) : sp_;                                       \
        float zm_ = dg_ ? -INFINITY : z_;                                     \
        lmax = fmaxf(lmax, zm_);                                              \
        if (zm_ > TAU) {                                                      \
            unsigned int p_ = atomicAdd(&wcnt[w], 1u);                        \
            if (p_ < 128u) { candk[w][p_] = __float_as_uint(z_);              \
                             candi[w][p_] = (unsigned int)(CC); }             \
            else ovf = true;                                                  \
        } } while (0)

    #pragma unroll
    for (int t = 0; t < 16; ++t) {
        float4 z4 = lr4[lane + (t << 6)];
        int cb = (lane << 2) + (t << 8);
        K1ELEM(z4.x, cb);
        K1ELEM(z4.y, cb + 1);
        K1ELEM(z4.z, cb + 2);
        K1ELEM(z4.w, cb + 3);
    }
#undef K1ELEM
    __syncthreads();

    for (int o = 1; o < 64; o <<= 1) {
        lsum += __shfl_xor(lsum, o);
        lmax = fmaxf(lmax, __shfl_xor(lmax, o));
    }
    if (lane == 0) { rowsum[row] = lsum; rowmaxk[row] = fkey(lmax); }

    const unsigned int n = wcnt[w];
    bool fb = (n < (unsigned)TOPK) || (n > 128u) || (__ballot(ovf) != 0ull);

    const unsigned int c0k = candk[w][lane], c1k = candk[w][lane + 64];
    const unsigned int i0  = candi[w][lane], i1  = candi[w][lane + 64];

    if (!fb) {
        unsigned int K = 0u;
        for (int b = 31; b >= 0; --b) {
            unsigned int tr = K | (1u << b);
            int cnt = __popcll(__ballot(c0k >= tr)) + __popcll(__ballot(c1k >= tr));
            if (cnt >= TOPK) K = tr;
        }
        unsigned long long m0g = __ballot(c0k > K), m1g = __ballot(c1k > K);
        unsigned long long m0e = __ballot(c0k == K), m1e = __ballot(c1k == K);
        int cnt_gt = __popcll(m0g) + __popcll(m1g);
        int kneed  = TOPK - cnt_gt;
        int eqc    = __popcll(m0e) + __popcll(m1e);
        if (eqc != kneed) {
            fb = true;   // boundary ties -> exact fallback
        } else {
            unsigned long long lmlt = (1ull << lane) - 1ull;
            int r0 = __popcll(m0g & lmlt);
            if (c0k > K) { skk[w][r0] = c0k; ski[w][r0] = i0; }
            int r1 = __popcll(m0g) + __popcll(m1g & lmlt);
            if (c1k > K) { skk[w][r1] = c1k; ski[w][r1] = i1; }
            int e0 = cnt_gt + __popcll(m0e & lmlt);
            if (c0k == K) { skk[w][e0] = c0k; ski[w][e0] = i0; }
            int e1 = cnt_gt + __popcll(m0e) + __popcll(m1e & lmlt);
            if (c1k == K) { skk[w][e1] = c1k; ski[w][e1] = i1; }
            lgkm0();   // in-wave LDS ordering
            if (lane < 32) {
                unsigned int my = skk[w][lane], mi = ski[w][lane];
                int rk = 0;
                #pragma unroll
                for (int k = 0; k < 32; ++k) {
                    unsigned int ok = skk[w][k];
                    rk += (int)((ok > my) || (ok == my && k < lane));
                }
                size_t rb = (size_t)row * TOPK;
                top_idx[rb + rk] = (int)mi;
                top_z [rb + rk] = __uint_as_float(my);
            }
        }
    }
    if (fb && lane == 0) flags[row] = 1u;

    // ---- fused ratio sample ----
    unsigned int hh = (unsigned int)row * 2654435761u;
    int j = (int)(((unsigned int)row + 1u + (hh % 4095u)) & 4095u);   // j != row
    const float4* tr4 = (const float4*)(text + (size_t)row * D);
    const float4* ir4 = (const float4*)(image + (size_t)j * D);
    float4 a0 = tr4[lane], b0 = ir4[lane];
    float4 a1 = tr4[lane + 64], b1 = ir4[lane + 64];
    float s3 = a0.x * b0.x + a0.y * b0.y + a0.z * b0.z + a0.w * b0.w
             + a1.x * b1.x + a1.y * b1.y + a1.z * b1.z + a1.w * b1.w;
    for (int o = 1; o < 64; o <<= 1) s3 += __shfl_xor(s3, o);
    if (lane == 0) ratio[row] = lr[j] / (s3 + 1e-8f);
}

// ---------------------------------------------------------------------------
// k1f: exact fallback for flagged rows (LDS radix select) + final value sort.
// Normally no-op.
// ---------------------------------------------------------------------------
__global__ __launch_bounds__(256) void k1_fallback(const float* __restrict__ logits,
                                                   const float* __restrict__ bias_p,
                                                   const unsigned int* __restrict__ flags,
                                                   int* __restrict__ top_idx,
                                                   float* __restrict__ top_z) {
    const int row = blockIdx.x;
    if (flags[row] == 0u) return;

    __shared__ unsigned int skey[B];
    __shared__ unsigned int histm[4 * 257 + 4];
    __shared__ unsigned int selb, selk;
    __shared__ int cnt_gt, cnt_eq;
    __shared__ int eqi[64];
    __shared__ unsigned int sk2[32], si2[32];

    const int tid = threadIdx.x, wid = tid >> 6, lane = tid & 63;
    const float bias = bias_p[0];
    const float* lr = logits + (size_t)row * B;

    #pragma unroll
    for (int t = 0; t < 16; ++t) {
        int c = tid + (t << 8);
        float z = lr[c] + bias;
        skey[c] = fkey((c == row) ? -INFINITY : z);
    }
    if (tid == 0) { cnt_gt = 0; cnt_eq = 0; }
    __syncthreads();

    unsigned int prefix = 0, kneed = TOPK;
    for (int r = 0; r < 4; ++r) {
        for (int i = tid; i < 4 * 257 + 4; i += 256) histm[i] = 0;
        __syncthreads();
        const int shift = 24 - 8 * r;
        #pragma unroll
        for (int t = 0; t < 16; ++t) {
            int c = tid + (t << 8);
            unsigned int kx = skey[c];
            bool part = (r == 0) || ((kx >> (32 - 8 * r)) == prefix);
            if (part) atomicAdd(&histm[wid * 257 + ((kx >> shift) & 255u)], 1u);
        }
        __syncthreads();
        unsigned int h = histm[tid] + histm[257 + tid] + histm[514 + tid] + histm[771 + tid];
        unsigned int s = h;
        for (int off = 1; off < 64; off <<= 1) {
            unsigned int o = __shfl_down(s, off);
            if (lane + off < 64) s += o;
        }
        if (lane == 0) histm[1028 + wid] = s;
        __syncthreads();
        unsigned int coarse = 0;
        for (int ww = wid + 1; ww < 4; ++ww) coarse += histm[1028 + ww];
        unsigned int incl = s + coarse, strict = incl - h;
        if (strict < kneed && kneed <= incl) { selb = (unsigned int)tid; selk = kneed - strict; }
        __syncthreads();
        prefix = (prefix << 8) | selb;
        kneed = selk;
        __syncthreads();
    }
    const unsigned int K32 = prefix;

    #pragma unroll
    for (int t = 0; t < 16; ++t) {
        int c = tid + (t << 8);
        unsigned int kx = skey[c];
        if (kx > K32) {
            int p = atomicAdd(&cnt_gt, 1);
            top_idx[(size_t)row * TOPK + p] = c;
            top_z [(size_t)row * TOPK + p] = finv(kx);
        } else if (kx == K32) {
            int p = atomicAdd(&cnt_eq, 1);
            if (p < 64) eqi[p] = c;
        }
    }
    __syncthreads();
    if (tid == 0) {
        int q = (int)kneed, base = cnt_gt, E = cnt_eq;
        float zv = finv(K32);
        if (E <= 64) {
            for (int s2 = 0; s2 < q; ++s2) {
                int best = 0x7FFFFFFF, bp = 0;
                for (int e = 0; e < E; ++e) { int ix = eqi[e]; if (ix < best) { best = ix; bp = e; } }
                eqi[bp] = 0x7FFFFFFF;
                top_idx[(size_t)row * TOPK + base + s2] = best;
                top_z [(size_t)row * TOPK + base + s2] = zv;
            }
        } else {
            int taken = 0;
            for (int c = 0; c < B && taken < q; ++c)
                if (skey[c] == K32) {
                    top_idx[(size_t)row * TOPK + base + taken] = c;
                    top_z [(size_t)row * TOPK + base + taken] = zv;
                    ++taken;
                }
        }
    }
    __syncthreads();
    if (tid < 32) {
        sk2[tid] = fkey(top_z[(size_t)row * TOPK + tid]);
        si2[tid] = (unsigned int)top_idx[(size_t)row * TOPK + tid];
    }
    __syncthreads();
    if (tid < 32) {
        unsigned int my = sk2[tid], mi = si2[tid];
        int rk = 0;
        #pragma unroll
        for (int k = 0; k < 32; ++k) {
            unsigned int ok = sk2[k];
            rk += (int)((ok > my) || (ok == my && k < tid));
        }
        top_idx[(size_t)row * TOPK + rk] = (int)mi;
        top_z [(size_t)row * TOPK + rk] = finv(my);
    }
}

// ---------------------------------------------------------------------------
// kmid: fused reduce + CSR build + 4-wave direct-gather Sinkhorn.
// Loop chain cut to 2-deep: (val,cid) packed in one 64-bit LDS word; run
// metadata preloaded to registers. 2 barriers/iter. m <= 2048.
// colPS packs ptr(12b)|comp(12b)|fill(8b) so the fill counter needs no
// separate LDS region.
// ---------------------------------------------------------------------------
__global__ __launch_bounds__(256) void kmid(const float* __restrict__ rowsum,
                                            const unsigned int* __restrict__ rowmaxk,
                                            const float* __restrict__ top_z,
                                            const int* __restrict__ top_idx,
                                            unsigned int* __restrict__ Mkey_g,
                                            double* __restrict__ base_acc_g,
                                            unsigned int* __restrict__ mcount_g,
                                            unsigned int* __restrict__ meta_g,
                                            float* __restrict__ vout) {
    __shared__ __align__(16) unsigned char SB[94208];
    unsigned long long* rpack = (unsigned long long*)(SB + 0);      // [2048] 16KB (val|cid<<32)
    unsigned long long* cpack = (unsigned long long*)(SB + 16384);  // [2048] 16KB (val|rid<<32)
    float*  usm      = (float*)(SB + 32768);                        // [2048] 8KB
    float*  vsm      = (float*)(SB + 40960);                        // [2048] 8KB
    unsigned* aRowSC = (unsigned*)(SB + 49152);                     // [2048] 8KB (start|cnt<<16)
    unsigned* aColSC = (unsigned*)(SB + 57344);                     // [2048] 8KB
    unsigned short* aColJ = (unsigned short*)(SB + 65536);          // [2048] 4KB
    unsigned* colPS  = (unsigned*)(SB + 69632);                     // [4096] 16KB ptr|comp<<12|fill<<24
    unsigned short* rowCnt = (unsigned short*)(SB + 86016);         // [4096] 8KB
    // build overlays:
    unsigned* colCnt = (unsigned*)(SB + 0);                         // 16KB over rpack
    unsigned* rowPS  = (unsigned*)(SB + 32768);                     // 16KB over usm+vsm (ptr|comp<<16)

    __shared__ double sdbl[4];
    __shared__ unsigned smax4[4];
    __shared__ float sMf;
    __shared__ unsigned mTot;
    __shared__ unsigned wq[4];
    __shared__ unsigned nrS, ncS;
    __shared__ float redA[4], redB[4];
    __shared__ unsigned mvf[4];

    const int tid = threadIdx.x, lane = tid & 63, wv = tid >> 6;

    // ---------- A: reduce ----------
    {
        double s = 0.0; unsigned mk = 0u;
        #pragma unroll
        for (int t = 0; t < 16; ++t) {
            int i = tid + (t << 8);
            s += (double)rowsum[i];
            unsigned k = rowmaxk[i];
            mk = (k > mk) ? k : mk;
        }
        for (int o = 1; o < 64; o <<= 1) {
            s += __shfl_xor(s, o);
            unsigned om = __shfl_xor(mk, o);
            mk = (om > mk) ? om : mk;
        }
        if (lane == 0) { sdbl[wv] = s; smax4[wv] = mk; }
        if (tid == 0) mTot = 0u;
    }
    __syncthreads();
    if (tid == 0) {
        *base_acc_g = sdbl[0] + sdbl[1] + sdbl[2] + sdbl[3];
        unsigned m2 = max(max(smax4[0], smax4[1]), max(smax4[2], smax4[3]));
        *Mkey_g = m2;
        sMf = finv(m2);
    }
    __syncthreads();
    const float M = sMf;
    const float zthr = M - CTHR;

    // ---------- B1: vectorized survivor count + col histogram ----------
    for (int i = tid; i < 4096; i += 256) colCnt[i] = 0u;
    __syncthreads();
    {
        unsigned myTot = 0;
        for (int i = 0; i < 16; ++i) {
            int r = (tid << 4) + i;
            const float4* tz4 = (const float4*)(top_z + (size_t)r * TOPK);
            int cnt = 0;
            #pragma unroll
            for (int q = 0; q < 8; ++q) {
                float4 t = tz4[q];
                cnt += (t.x > zthr) + (t.y > zthr) + (t.z > zthr) + (t.w > zthr);
            }
            rowCnt[r] = (unsigned short)cnt;
            myTot += (unsigned)cnt;
            const int* tj = top_idx + (size_t)r * TOPK;
            for (int k = 0; k < cnt; ++k)
                atomicAdd(&colCnt[(unsigned)tj[k]], 1u);
        }
        atomicAdd(&mTot, myTot);
    }
    __syncthreads();
    const int m = (int)mTot;
    if (tid == 0) { mcount_g[0] = (unsigned)m; meta_g[0] = (m > MCAP) ? 1u : 0u; }
    if (m > MCAP) return;

    // ---------- B2a: row scan -> rowPS (ptr|comp<<16) + aRowSC ----------
    {
        unsigned pre[16]; unsigned tsum = 0;
        #pragma unroll
        for (int i = 0; i < 16; ++i) {
            unsigned c2 = rowCnt[(tid << 4) + i];
            unsigned val = c2 | ((c2 ? 1u : 0u) << 16);
            pre[i] = tsum; tsum += val;
        }
        unsigned sc = tsum;
        for (int o = 1; o < 64; o <<= 1) {
            unsigned n2 = __shfl_up(sc, o);
            if (lane >= o) sc += n2;
        }
        if (lane == 63) wq[wv] = sc;
        __syncthreads();
        unsigned woff = 0;
        for (int w2 = 0; w2 < wv; ++w2) woff += wq[w2];
        unsigned base0 = woff + sc - tsum;
        #pragma unroll
        for (int i = 0; i < 16; ++i) {
            int r = (tid << 4) + i;
            unsigned pfx = base0 + pre[i];
            rowPS[r] = pfx;
            unsigned c2 = rowCnt[r];
            if (c2) aRowSC[pfx >> 16] = (pfx & 0xFFFFu) | (c2 << 16);
        }
        if (tid == 255) nrS = (base0 + tsum) >> 16;
    }
    __syncthreads();
    // ---------- B2b: col scan -> colPS (12/12 packing, fill bits clear) ----------
    {
        unsigned pre[16]; unsigned tsum = 0;
        #pragma unroll
        for (int i = 0; i < 16; ++i) {
            unsigned c2 = colCnt[(tid << 4) + i];
            unsigned val = c2 | ((c2 ? 1u : 0u) << 12);
            pre[i] = tsum; tsum += val;
        }
        unsigned sc = tsum;
        for (int o = 1; o < 64; o <<= 1) {
            unsigned n2 = __shfl_up(sc, o);
            if (lane >= o) sc += n2;
        }
        if (lane == 63) wq[wv] = sc;
        __syncthreads();
        unsigned woff = 0;
        for (int w2 = 0; w2 < wv; ++w2) woff += wq[w2];
        unsigned base0 = woff + sc - tsum;
        #pragma unroll
        for (int i = 0; i < 16; ++i) {
            int j = (tid << 4) + i;
            unsigned pfx = base0 + pre[i];
            unsigned c2 = colCnt[j];
            colPS[j] = pfx;                    // fill bits (24+) are zero
            if (c2) {
                unsigned cc = pfx >> 12;
                aColSC[cc] = (pfx & 0xFFFu) | (c2 << 16);
                aColJ[cc] = (unsigned short)j;
            }
        }
        if (tid == 255) ncS = (base0 + tsum) >> 12;
    }
    __syncthreads();
    {   // max col count guard (fill field is 8 bits -> cnt <= 255; use 64 cap)
        unsigned mcc = 0;
        #pragma unroll
        for (int i = 0; i < 16; ++i) mcc = max(mcc, colCnt[(tid << 4) + i]);
        for (int o = 1; o < 64; o <<= 1) { unsigned t2 = __shfl_xor(mcc, o); mcc = max(mcc, t2); }
        if (lane == 0) smax4[wv] = mcc;
    }
    __syncthreads();
    {
        unsigned mx = max(max(smax4[0], smax4[1]), max(smax4[2], smax4[3]));
        if (tid == 0 && mx > 64u) meta_g[0] = 1u;
        if (mx > 64u) return;   // uniform
    }
    __syncthreads();   // colCnt fully consumed -> rpack overlay may be written

    // ---------- B3: fill packed CSR (fill counter lives in colPS bits 24+) ----------
    for (int i = 0; i < 16; ++i) {
        int r = (tid << 4) + i;
        int cnt = rowCnt[r];
        if (!cnt) continue;
        unsigned rps = rowPS[r];
        unsigned rptr = rps & 0xFFFFu, rcomp = rps >> 16;
        const float* tz = top_z + (size_t)r * TOPK;
        const int* tj = top_idx + (size_t)r * TOPK;
        for (int k = 0; k < cnt; ++k) {
            float c = fmaxf(M - tz[k], 0.0f);
            float e = expf(-(c / OT_EPS_F));
            unsigned vb = __float_as_uint(e - FLOORK);
            unsigned j = (unsigned)tj[k];
            unsigned old = atomicAdd(&colPS[j], 1u << 24);
            unsigned cptr = old & 0xFFFu, ccomp = (old >> 12) & 0xFFFu, prior = old >> 24;
            rpack[rptr + (unsigned)k] = (unsigned long long)vb | ((unsigned long long)ccomp << 32);
            cpack[cptr + prior]       = (unsigned long long)vb | ((unsigned long long)rcomp << 32);
        }
    }
    __syncthreads();
    // ---------- B4: init scaling tables (frees rowPS overlay of usm/vsm) ----------
    for (int i = tid; i < 2048; i += 256) { usm[i] = 1.0f; vsm[i] = 1.0f; }

    // ---------- preload run metadata to registers ----------
    const int nr = (int)nrS, nc = (int)ncS;
    unsigned rme[8], cme[8];
    #pragma unroll
    for (int s = 0; s < 8; ++s) {
        int i = tid + (s << 8);
        rme[s] = (i < nr) ? aRowSC[i] : 0u;
        cme[s] = (i < nc) ? aColSC[i] : 0u;
    }
    __syncthreads();

    // ---------- D: 4-wave direct-gather Sinkhorn, 2 barriers/iter ----------
    float u0 = 1.0f, v0 = 1.0f;
    float SvA = (float)nc;
    for (int it = 0; it < 30; ++it) {
        const float bgu = FLOORK * ((float)(B - nc) * v0 + SvA) + 1e-8f;
        const float u0n = AMASS * rcpf_(bgu);
        float SuP = 0.0f;
        #pragma unroll
        for (int s = 0; s < 8; ++s) {
            unsigned me = rme[s];
            unsigned ct = me >> 16;
            if (ct) {
                unsigned st = me & 0xFFFFu;
                float ss = 0.0f;
                for (unsigned k = 0; k < ct; ++k) {
                    unsigned long long wd = rpack[st + k];
                    ss += __uint_as_float((unsigned)wd) * vsm[(unsigned)(wd >> 32)];
                }
                float u = AMASS * rcpf_(bgu + ss);
                usm[tid + (s << 8)] = u;
                SuP += u;
            }
        }
        SuP = wsum64(SuP);
        if (lane == 0) redA[wv] = SuP;
        __syncthreads();                                   // (1) usm + redA ready
        const float Su = redA[0] + redA[1] + redA[2] + redA[3];
        const float bgv = FLOORK * ((float)(B - nr) * u0n + Su) + 1e-8f;
        const float v0n = AMASS * rcpf_(bgv);
        float SvP = 0.0f; bool moved = false;
        #pragma unroll
        for (int s = 0; s < 8; ++s) {
            unsigned me = cme[s];
            unsigned ct = me >> 16;
            if (ct) {
                unsigned st = me & 0xFFFFu;
                float ss = 0.0f;
                for (unsigned k = 0; k < ct; ++k) {
                    unsigned long long wd = cpack[st + k];
                    ss += __uint_as_float((unsigned)wd) * usm[(unsigned)(wd >> 32)];
                }
                float vn = AMASS * rcpf_(bgv + ss);
                int i2 = tid + (s << 8);
                float vold = vsm[i2];
                if (fabsf(vn - vold) > EPS_L * vold) moved = true;
                vsm[i2] = vn;
                SvP += vn;
            }
        }
        SvP = wsum64(SvP);
        if (lane == 0) { redB[wv] = SvP; mvf[wv] = (__ballot(moved) != 0ull) ? 1u : 0u; }
        __syncthreads();                                   // (2) vsm + redB + mvf ready
        SvA = redB[0] + redB[1] + redB[2] + redB[3];
        const bool conv = ((mvf[0] | mvf[1] | mvf[2] | mvf[3]) == 0u) &&
                          (fabsf(v0n - v0) <= EPS_L * v0) &&
                          (fabsf(u0n - u0) <= EPS_L * u0);
        u0 = u0n; v0 = v0n;
        if (conv) break;   // uniform
    }

    // ---------- epilogue: fill background v0, overwrite active cols ----------
    {
        float4* vo4 = (float4*)vout;
        const float4 fill = make_float4(v0, v0, v0, v0);
        for (int t2 = tid; t2 < 1024; t2 += 256) vo4[t2] = fill;
        __syncthreads();
        for (int i = tid; i < nc; i += 256)
            vout[aColJ[i]] = vsm[i];
    }
}

// ---------------------------------------------------------------------------
// k4_fb: list-free global Sinkhorn fallback (meta[0]==1 only). Correctness path.
// ---------------------------------------------------------------------------
__global__ __launch_bounds__(256) void k4_fb(const unsigned int* __restrict__ meta,
                                             const unsigned int* __restrict__ Mkey,
                                             const float* __restrict__ top_z,
                                             const int* __restrict__ top_idx,
                                             float* __restrict__ evals,
                                             float* __restrict__ gv,
                                             float* __restrict__ ga,
                                             float* __restrict__ gb,
                                             float* __restrict__ vout) {
    if (meta[0] == 0u) return;
    __shared__ float red[4];
    __shared__ float bc;
    const int tid = threadIdx.x, lane = tid & 63, wv = tid >> 6;
    const float M = finv(Mkey[0]);

    for (int c = tid; c < B * TOPK; c += 256) {
        float cc = fmaxf(M - top_z[c], 0.0f);
        float e = 0.0f;
        if (cc < CPRE) {
            float t = expf(-(cc / OT_EPS_F));
            if (t > FLOORK) e = t - FLOORK;
        }
        evals[c] = e;
    }
    for (int i = tid; i < B; i += 256) gv[i] = 1.0f;
    __syncthreads();

    for (int it = 0; it < 30; ++it) {
        float s = 0.0f;
        for (int i = tid; i < B; i += 256) { s += gv[i]; ga[i] = 0.0f; }
        for (int o = 1; o < 64; o <<= 1) s += __shfl_xor(s, o);
        if (lane == 0) red[wv] = s;
        __syncthreads();
        if (tid == 0) bc = red[0] + red[1] + red[2] + red[3];
        __syncthreads();
        const float bgu = FLOORK * bc + 1e-8f;
        for (int c = tid; c < B * TOPK; c += 256) {
            float a = evals[c];
            if (a > 0.0f) atomicAdd(&ga[c >> 5], a * gv[top_idx[c]]);
        }
        __syncthreads();
        float su = 0.0f;
        for (int i = tid; i < B; i += 256) { su += AMASS / (bgu + ga[i]); gb[i] = 0.0f; }
        for (int o = 1; o < 64; o <<= 1) su += __shfl_xor(su, o);
        if (lane == 0) red[wv] = su;
        __syncthreads();
        if (tid == 0) bc = red[0] + red[1] + red[2] + red[3];
        __syncthreads();
        const float bgv = FLOORK * bc + 1e-8f;
        for (int c = tid; c < B * TOPK; c += 256) {
            float a = evals[c];
            if (a > 0.0f) {
                float u = AMASS / (bgu + ga[c >> 5]);
                atomicAdd(&gb[top_idx[c]], a * u);
            }
        }
        __syncthreads();
        for (int i = tid; i < B; i += 256) gv[i] = AMASS / (bgv + gb[i]);
        __syncthreads();
    }
    for (int i = tid; i < B; i += 256) vout[i] = gv[i];
}

// ---------------------------------------------------------------------------
// k5: per row: weights = K*v (u cancels), synthetic negative, normalize,
// dot with text row.
// ---------------------------------------------------------------------------
__global__ __launch_bounds__(256) void k5_synth(const int* __restrict__ top_idx,
                                                const float* __restrict__ top_z,
                                                const unsigned int* __restrict__ Mkey,
                                                const float* __restrict__ v,
                                                const float* __restrict__ image,
                                                const float* __restrict__ text,
                                                float* __restrict__ synth_sim) {
    __shared__ float sw[TOPK];
    __shared__ int   sj[TOPK];
    __shared__ float red[4];
    __shared__ float bcast;

    const int row = blockIdx.x, tid = threadIdx.x;
    const int wid = tid >> 6, lane = tid & 63;
    const float M = finv(Mkey[0]);

    if (tid < 64) {
        float wt = 0.0f;
        if (tid < TOPK) {
            int j = top_idx[(size_t)row * TOPK + tid];
            float z = top_z[(size_t)row * TOPK + tid];
            float c = fmaxf(M - z, 0.0f);
            float K = fmaxf(expf(-(c / OT_EPS_F)), FLOORK);
            wt = K * v[j];
            sj[tid] = j;
            sw[tid] = wt;
        }
        float s = wt;
        for (int off = 32; off; off >>= 1) s += __shfl_down(s, off);
        if (tid == 0) bcast = fmaxf(s, 1e-8f);
    }
    __syncthreads();
    if (tid < TOPK) sw[tid] = sw[tid] / bcast;
    __syncthreads();

    float s0 = 0.0f, s1 = 0.0f;
    for (int t = 0; t < TOPK; ++t) {
        float wv2 = sw[t];
        const float* img = image + (size_t)sj[t] * D;
        s0 += wv2 * img[tid];
        s1 += wv2 * img[tid + 256];
    }
    float nn = s0 * s0 + s1 * s1;
    for (int off = 32; off; off >>= 1) nn += __shfl_down(nn, off);
    if (lane == 0) red[wid] = nn;
    __syncthreads();
    float norm2 = red[0] + red[1] + red[2] + red[3];
    float den = sqrtf(norm2) + 1e-8f;
    float p = (s0 / den) * text[(size_t)row * D + tid] +
              (s1 / den) * text[(size_t)row * D + tid + 256];
    __syncthreads();
    for (int off = 32; off; off >>= 1) p += __shfl_down(p, off);
    if (lane == 0) red[wid] = p;
    __syncthreads();
    if (tid == 0) synth_sim[row] = red[0] + red[1] + red[2] + red[3];
}

// ---------------------------------------------------------------------------
// k78: median of ratio via radix select, then gate + final combine.
// ---------------------------------------------------------------------------
__global__ __launch_bounds__(256) void k78_final(const float* __restrict__ ratio,
                                                 const float* __restrict__ synth_sim,
                                                 const double* __restrict__ base_acc,
                                                 float* __restrict__ out) {
    __shared__ unsigned int skey[B];
    __shared__ unsigned int histm[4 * 257 + 4];
    __shared__ unsigned int selb, selk;
    __shared__ double rs[4];
    __shared__ float rg[4];

    const int tid = threadIdx.x, wid = tid >> 6, lane = tid & 63;

    #pragma unroll
    for (int t = 0; t < 16; ++t) {
        int c = tid + (t << 8);
        skey[c] = fkey(ratio[c]);
    }
    __syncthreads();

    unsigned int prefix = 0, kneed = 2048;
    for (int r = 0; r < 4; ++r) {
        for (int i = tid; i < 4 * 257 + 4; i += 256) histm[i] = 0;
        __syncthreads();
        const int shift = 24 - 8 * r;
        unsigned int cb = 0xFFFFFFFFu, cc = 0;
        #pragma unroll
        for (int t = 0; t < 16; ++t) {
            unsigned int kx = skey[tid + (t << 8)];
            bool part = (r == 0) || ((kx >> (32 - 8 * r)) == prefix);
            if (part) {
                unsigned int bin = (kx >> shift) & 255u;
                if (bin == cb) ++cc;
                else {
                    if (cc) atomicAdd(&histm[wid * 257 + cb], cc);
                    cb = bin; cc = 1;
                }
            }
        }
        if (cc) atomicAdd(&histm[wid * 257 + cb], cc);
        __syncthreads();
        unsigned int h = histm[tid] + histm[257 + tid] + histm[514 + tid] + histm[771 + tid];
        unsigned int s = h;
        for (int off = 1; off < 64; off <<= 1) {
            unsigned int o = __shfl_down(s, off);
            if (lane + off < 64) s += o;
        }
        if (lane == 0) histm[1028 + wid] = s;
        __syncthreads();
        unsigned int coarse = 0;
        for (int w = wid + 1; w < 4; ++w) coarse += histm[1028 + w];
        unsigned int incl = s + coarse, strict = incl - h;
        if (strict < kneed && kneed <= incl) { selb = (unsigned int)tid; selk = kneed - strict; }
        __syncthreads();
        prefix = (prefix << 8) | selb;
        kneed = selk;
        __syncthreads();
    }
    const unsigned int KA = prefix;
    const unsigned int g = 2048u - kneed;

    unsigned int ec = 0, mb = 0;
    #pragma unroll
    for (int t = 0; t < 16; ++t) {
        unsigned int kx = skey[tid + (t << 8)];
        if (kx == KA) ++ec;
        else if (kx < KA && kx > mb) mb = kx;
    }
    for (int off = 1; off < 64; off <<= 1) {
        ec += __shfl_xor(ec, off);
        unsigned int o = __shfl_xor(mb, off);
        mb = (o > mb) ? o : mb;
    }
    __syncthreads();
    if (lane == 0) { histm[wid] = ec; histm[8 + wid] = mb; }
    __syncthreads();
    unsigned int E  = histm[0] + histm[1] + histm[2] + histm[3];
    unsigned int MB = max(max(histm[8], histm[9]), max(histm[10], histm[11]));
    unsigned int KB = (g + E >= 2049u) ? KA : MB;
    const float scale = 0.5f * (finv(KA) + finv(KB));

    double lsd = 0.0; float gs = 0.0f;
    #pragma unroll
    for (int t = 0; t < 16; ++t) {
        float sl = scale * synth_sim[tid + (t << 8)];
        if (sl > -0.05f) { gs += 1.0f; lsd += (double)softplusf(sl); }
    }
    for (int off = 1; off < 64; off <<= 1) {
        lsd += __shfl_xor(lsd, off);
        gs  += __shfl_xor(gs, off);
    }
    if (lane == 0) { rs[wid] = lsd; rg[wid] = gs; }
    __syncthreads();
    if (tid == 0) {
        double L = rs[0] + rs[1] + rs[2] + rs[3];
        float  G = rg[0] + rg[1] + rg[2] + rg[3];
        double base = base_acc[0] / ((double)B * (double)B);
        double synth = (G > 0.0f) ? (L / ((double)G + 1e-8)) : 0.0;
        out[0] = (float)(base + 0.5 * synth);
    }
}

extern "C" void kernel_launch(void* const* d_in, const int* in_sizes, int n_in,
                              void* d_out, int out_size, void* d_ws, size_t ws_size,
                              hipStream_t stream) {
    const float* logits = (const float*)d_in[0];
    const float* text   = (const float*)d_in[1];
    const float* image  = (const float*)d_in[2];
    const float* bias   = (const float*)d_in[3];

    char* ws = (char*)d_ws;
    double*       base_acc = (double*)(ws + 0);
    unsigned int* mcount   = (unsigned int*)(ws + 8);
    unsigned int* Mkey     = (unsigned int*)(ws + 12);
    unsigned int* meta     = (unsigned int*)(ws + 16);
    unsigned int* flags    = (unsigned int*)(ws + 64);            // 16 KB
    float*        rowsum   = (float*)(ws + 64 + 16384);
    unsigned int* rowmaxk  = (unsigned int*)(rowsum + B);
    float*        v        = (float*)(rowmaxk + B);
    float*        sim      = v + B;
    float*        ratio    = sim + B;
    float*        gv       = ratio + B;
    float*        ga       = gv + B;
    float*        gb       = ga + B;
    int*          top_idx  = (int*)(gb + B);
    float*        top_z    = (float*)(top_idx + (size_t)B * TOPK);
    float*        evals    = (float*)(top_z + (size_t)B * TOPK);

    // zero: header + flags (k1_fallback gating)
    (void)hipMemsetAsync(ws, 0, 64 + 16384, stream);

    k1_row     <<<B / 4, 256, 0, stream>>>(logits, text, image, bias, rowsum, rowmaxk,
                                           top_idx, top_z, ratio, flags);
    k1_fallback<<<B, 256, 0, stream>>>(logits, bias, flags, top_idx, top_z);
    kmid       <<<1, 256, 0, stream>>>(rowsum, rowmaxk, top_z, top_idx, Mkey, base_acc,
                                       mcount, meta, v);
    k4_fb      <<<1, 256, 0, stream>>>(meta, Mkey, top_z, top_idx, evals, gv, ga, gb, v);
    k5_synth   <<<B, 256, 0, stream>>>(top_idx, top_z, Mkey, v, image, text, sim);
    k78_final  <<<1, 256, 0, stream>>>(ratio, sim, base_acc, (float*)d_out);
}

// Round 19
// 154.685 us; speedup vs baseline: 2.3351x; 1.2483x over previous
//
#include <hip/hip_runtime.h>
#include <math.h>

#define B 4096
#define D 512
#define TOPK 32
#define MCAP 2048

constexpr float OT_EPS_F = 0.05f;
constexpr float FLOORK   = 1e-12f;
constexpr float AMASS    = 1.0f / 4096.0f;   // exact 2^-12
constexpr float TAU      = 1.8f;             // k1 candidate prefilter threshold
constexpr float EPS_L    = 1e-4f;            // loop convergence tolerance (bounded drift)
constexpr float CPRE     = 1.45f;            // conservative cost prefilter (fallback path)
constexpr float CTHR     = 1.3815510f;       // analytic: e>1e-12 <=> c < 0.05*ln(1e12)

// fast softplus via HW transcendentals (v_exp_f32 / v_log_f32), ~1e-7 abs err
__device__ __forceinline__ float softplusf(float x) {
    return fmaxf(x, 0.0f) + __logf(1.0f + __expf(-fabsf(x)));
}
__device__ __forceinline__ unsigned int fkey(float f) {
    unsigned int x = __float_as_uint(f);
    return x ^ ((x & 0x80000000u) ? 0xFFFFFFFFu : 0x80000000u);
}
__device__ __forceinline__ float finv(unsigned int k) {
    unsigned int x = (k & 0x80000000u) ? (k ^ 0x80000000u) : ~k;
    return __uint_as_float(x);
}
__device__ __forceinline__ float rcpf_(float x) { return __builtin_amdgcn_rcpf(x); }
__device__ __forceinline__ void lgkm0() {
    asm volatile("s_waitcnt lgkmcnt(0)" ::: "memory");
    __builtin_amdgcn_sched_barrier(0);
}
#define DPPADD(x, ctrl) ((x) + __int_as_float(__builtin_amdgcn_update_dpp(0, __float_as_int(x), (ctrl), 0xf, 0xf, false)))
__device__ __forceinline__ float wsum64(float x) {
    x = DPPADD(x, 0x111);
    x = DPPADD(x, 0x112);
    x = DPPADD(x, 0x114);
    x = DPPADD(x, 0x118);
    x = DPPADD(x, 0x142);
    x = DPPADD(x, 0x143);
    return __int_as_float(__builtin_amdgcn_readlane(__float_as_int(x), 63));
}

// ---------------------------------------------------------------------------
// k1: wave-per-row (4 rows / 256-block). HW-transcendental softplus, ballot
// top-32, VALUE-DESCENDING emission (LDS stage + 32-way rank sort) so kmid's
// prefix property holds by construction. Unchanged.
// ---------------------------------------------------------------------------
__global__ __launch_bounds__(256) void k1_row(const float* __restrict__ logits,
                                              const float* __restrict__ text,
                                              const float* __restrict__ image,
                                              const float* __restrict__ bias_p,
                                              float* __restrict__ rowsum,
                                              unsigned int* __restrict__ rowmaxk,
                                              int* __restrict__ top_idx,
                                              float* __restrict__ top_z,
                                              float* __restrict__ ratio,
                                              unsigned int* __restrict__ flags) {
    __shared__ unsigned int candk[4][128];
    __shared__ unsigned int candi[4][128];
    __shared__ unsigned int wcnt[4];
    __shared__ unsigned int skk[4][32];
    __shared__ unsigned int ski[4][32];

    const int tid = threadIdx.x, w = tid >> 6, lane = tid & 63;
    const int row = (blockIdx.x << 2) + w;
    const float bias = bias_p[0];
    const float* lr = logits + (size_t)row * B;
    const float4* lr4 = (const float4*)lr;

    if (lane == 0) wcnt[w] = 0;
    candk[w][lane] = 0; candk[w][lane + 64] = 0;

    float lsum = 0.0f, lmax = -INFINITY;
    bool ovf = false;

#define K1ELEM(ZV, CC) do {                                                   \
        float z_ = (ZV) + bias;                                               \
        bool dg_ = ((CC) == row);                                             \
        float sp_ = softplusf(z_);                                            \
        lsum += dg_ ? (sp_ - z_) : sp_;                                       \
        float zm_ = dg_ ? -INFINITY : z_;                                     \
        lmax = fmaxf(lmax, zm_);                                              \
        if (zm_ > TAU) {                                                      \
            unsigned int p_ = atomicAdd(&wcnt[w], 1u);                        \
            if (p_ < 128u) { candk[w][p_] = __float_as_uint(z_);              \
                             candi[w][p_] = (unsigned int)(CC); }             \
            else ovf = true;                                                  \
        } } while (0)

    #pragma unroll
    for (int t = 0; t < 16; ++t) {
        float4 z4 = lr4[lane + (t << 6)];
        int cb = (lane << 2) + (t << 8);
        K1ELEM(z4.x, cb);
        K1ELEM(z4.y, cb + 1);
        K1ELEM(z4.z, cb + 2);
        K1ELEM(z4.w, cb + 3);
    }
#undef K1ELEM
    __syncthreads();

    for (int o = 1; o < 64; o <<= 1) {
        lsum += __shfl_xor(lsum, o);
        lmax = fmaxf(lmax, __shfl_xor(lmax, o));
    }
    if (lane == 0) { rowsum[row] = lsum; rowmaxk[row] = fkey(lmax); }

    const unsigned int n = wcnt[w];
    bool fb = (n < (unsigned)TOPK) || (n > 128u) || (__ballot(ovf) != 0ull);

    const unsigned int c0k = candk[w][lane], c1k = candk[w][lane + 64];
    const unsigned int i0  = candi[w][lane], i1  = candi[w][lane + 64];

    if (!fb) {
        unsigned int K = 0u;
        for (int b = 31; b >= 0; --b) {
            unsigned int tr = K | (1u << b);
            int cnt = __popcll(__ballot(c0k >= tr)) + __popcll(__ballot(c1k >= tr));
            if (cnt >= TOPK) K = tr;
        }
        unsigned long long m0g = __ballot(c0k > K), m1g = __ballot(c1k > K);
        unsigned long long m0e = __ballot(c0k == K), m1e = __ballot(c1k == K);
        int cnt_gt = __popcll(m0g) + __popcll(m1g);
        int kneed  = TOPK - cnt_gt;
        int eqc    = __popcll(m0e) + __popcll(m1e);
        if (eqc != kneed) {
            fb = true;   // boundary ties -> exact fallback
        } else {
            unsigned long long lmlt = (1ull << lane) - 1ull;
            int r0 = __popcll(m0g & lmlt);
            if (c0k > K) { skk[w][r0] = c0k; ski[w][r0] = i0; }
            int r1 = __popcll(m0g) + __popcll(m1g & lmlt);
            if (c1k > K) { skk[w][r1] = c1k; ski[w][r1] = i1; }
            int e0 = cnt_gt + __popcll(m0e & lmlt);
            if (c0k == K) { skk[w][e0] = c0k; ski[w][e0] = i0; }
            int e1 = cnt_gt + __popcll(m0e) + __popcll(m1e & lmlt);
            if (c1k == K) { skk[w][e1] = c1k; ski[w][e1] = i1; }
            lgkm0();   // in-wave LDS ordering
            if (lane < 32) {
                unsigned int my = skk[w][lane], mi = ski[w][lane];
                int rk = 0;
                #pragma unroll
                for (int k = 0; k < 32; ++k) {
                    unsigned int ok = skk[w][k];
                    rk += (int)((ok > my) || (ok == my && k < lane));
                }
                size_t rb = (size_t)row * TOPK;
                top_idx[rb + rk] = (int)mi;
                top_z [rb + rk] = __uint_as_float(my);
            }
        }
    }
    if (fb && lane == 0) flags[row] = 1u;

    // ---- fused ratio sample ----
    unsigned int hh = (unsigned int)row * 2654435761u;
    int j = (int)(((unsigned int)row + 1u + (hh % 4095u)) & 4095u);   // j != row
    const float4* tr4 = (const float4*)(text + (size_t)row * D);
    const float4* ir4 = (const float4*)(image + (size_t)j * D);
    float4 a0 = tr4[lane], b0 = ir4[lane];
    float4 a1 = tr4[lane + 64], b1 = ir4[lane + 64];
    float s3 = a0.x * b0.x + a0.y * b0.y + a0.z * b0.z + a0.w * b0.w
             + a1.x * b1.x + a1.y * b1.y + a1.z * b1.z + a1.w * b1.w;
    for (int o = 1; o < 64; o <<= 1) s3 += __shfl_xor(s3, o);
    if (lane == 0) ratio[row] = lr[j] / (s3 + 1e-8f);
}

// ---------------------------------------------------------------------------
// k1f: exact fallback for flagged rows (LDS radix select) + final value sort.
// Normally no-op. Unchanged.
// ---------------------------------------------------------------------------
__global__ __launch_bounds__(256) void k1_fallback(const float* __restrict__ logits,
                                                   const float* __restrict__ bias_p,
                                                   const unsigned int* __restrict__ flags,
                                                   int* __restrict__ top_idx,
                                                   float* __restrict__ top_z) {
    const int row = blockIdx.x;
    if (flags[row] == 0u) return;

    __shared__ unsigned int skey[B];
    __shared__ unsigned int histm[4 * 257 + 4];
    __shared__ unsigned int selb, selk;
    __shared__ int cnt_gt, cnt_eq;
    __shared__ int eqi[64];
    __shared__ unsigned int sk2[32], si2[32];

    const int tid = threadIdx.x, wid = tid >> 6, lane = tid & 63;
    const float bias = bias_p[0];
    const float* lr = logits + (size_t)row * B;

    #pragma unroll
    for (int t = 0; t < 16; ++t) {
        int c = tid + (t << 8);
        float z = lr[c] + bias;
        skey[c] = fkey((c == row) ? -INFINITY : z);
    }
    if (tid == 0) { cnt_gt = 0; cnt_eq = 0; }
    __syncthreads();

    unsigned int prefix = 0, kneed = TOPK;
    for (int r = 0; r < 4; ++r) {
        for (int i = tid; i < 4 * 257 + 4; i += 256) histm[i] = 0;
        __syncthreads();
        const int shift = 24 - 8 * r;
        #pragma unroll
        for (int t = 0; t < 16; ++t) {
            int c = tid + (t << 8);
            unsigned int kx = skey[c];
            bool part = (r == 0) || ((kx >> (32 - 8 * r)) == prefix);
            if (part) atomicAdd(&histm[wid * 257 + ((kx >> shift) & 255u)], 1u);
        }
        __syncthreads();
        unsigned int h = histm[tid] + histm[257 + tid] + histm[514 + tid] + histm[771 + tid];
        unsigned int s = h;
        for (int off = 1; off < 64; off <<= 1) {
            unsigned int o = __shfl_down(s, off);
            if (lane + off < 64) s += o;
        }
        if (lane == 0) histm[1028 + wid] = s;
        __syncthreads();
        unsigned int coarse = 0;
        for (int ww = wid + 1; ww < 4; ++ww) coarse += histm[1028 + ww];
        unsigned int incl = s + coarse, strict = incl - h;
        if (strict < kneed && kneed <= incl) { selb = (unsigned int)tid; selk = kneed - strict; }
        __syncthreads();
        prefix = (prefix << 8) | selb;
        kneed = selk;
        __syncthreads();
    }
    const unsigned int K32 = prefix;

    #pragma unroll
    for (int t = 0; t < 16; ++t) {
        int c = tid + (t << 8);
        unsigned int kx = skey[c];
        if (kx > K32) {
            int p = atomicAdd(&cnt_gt, 1);
            top_idx[(size_t)row * TOPK + p] = c;
            top_z [(size_t)row * TOPK + p] = finv(kx);
        } else if (kx == K32) {
            int p = atomicAdd(&cnt_eq, 1);
            if (p < 64) eqi[p] = c;
        }
    }
    __syncthreads();
    if (tid == 0) {
        int q = (int)kneed, base = cnt_gt, E = cnt_eq;
        float zv = finv(K32);
        if (E <= 64) {
            for (int s2 = 0; s2 < q; ++s2) {
                int best = 0x7FFFFFFF, bp = 0;
                for (int e = 0; e < E; ++e) { int ix = eqi[e]; if (ix < best) { best = ix; bp = e; } }
                eqi[bp] = 0x7FFFFFFF;
                top_idx[(size_t)row * TOPK + base + s2] = best;
                top_z [(size_t)row * TOPK + base + s2] = zv;
            }
        } else {
            int taken = 0;
            for (int c = 0; c < B && taken < q; ++c)
                if (skey[c] == K32) {
                    top_idx[(size_t)row * TOPK + base + taken] = c;
                    top_z [(size_t)row * TOPK + base + taken] = zv;
                    ++taken;
                }
        }
    }
    __syncthreads();
    if (tid < 32) {
        sk2[tid] = fkey(top_z[(size_t)row * TOPK + tid]);
        si2[tid] = (unsigned int)top_idx[(size_t)row * TOPK + tid];
    }
    __syncthreads();
    if (tid < 32) {
        unsigned int my = sk2[tid], mi = si2[tid];
        int rk = 0;
        #pragma unroll
        for (int k = 0; k < 32; ++k) {
            unsigned int ok = sk2[k];
            rk += (int)((ok > my) || (ok == my && k < tid));
        }
        top_idx[(size_t)row * TOPK + rk] = (int)mi;
        top_z [(size_t)row * TOPK + rk] = finv(my);
    }
}

// ---------------------------------------------------------------------------
// kmid: fused reduce + CSR build + 16-wave direct-gather Sinkhorn (1024 thr).
// Per-thread owner count cut 8->2 per phase (the serial latency chain).
// 2 barriers/iter. m <= 2048. Packed 64-bit CSR words.
// ---------------------------------------------------------------------------
__global__ __launch_bounds__(1024) void kmid(const float* __restrict__ rowsum,
                                             const unsigned int* __restrict__ rowmaxk,
                                             const float* __restrict__ top_z,
                                             const int* __restrict__ top_idx,
                                             unsigned int* __restrict__ Mkey_g,
                                             double* __restrict__ base_acc_g,
                                             unsigned int* __restrict__ mcount_g,
                                             unsigned int* __restrict__ meta_g,
                                             float* __restrict__ vout) {
    __shared__ __align__(16) unsigned char SB[94208];
    unsigned long long* rpack = (unsigned long long*)(SB + 0);      // [2048] 16KB (val|cid<<32)
    unsigned long long* cpack = (unsigned long long*)(SB + 16384);  // [2048] 16KB (val|rid<<32)
    float*  usm      = (float*)(SB + 32768);                        // [2048] 8KB
    float*  vsm      = (float*)(SB + 40960);                        // [2048] 8KB
    unsigned* aRowSC = (unsigned*)(SB + 49152);                     // [2048] 8KB (start|cnt<<16)
    unsigned* aColSC = (unsigned*)(SB + 57344);                     // [2048] 8KB
    unsigned short* aColJ = (unsigned short*)(SB + 65536);          // [2048] 4KB
    unsigned* colPS  = (unsigned*)(SB + 69632);                     // [4096] 16KB ptr|comp<<12|fill<<24
    unsigned short* rowCnt = (unsigned short*)(SB + 86016);         // [4096] 8KB
    // build overlays:
    unsigned* colCnt = (unsigned*)(SB + 0);                         // 16KB over rpack
    unsigned* rowPS  = (unsigned*)(SB + 32768);                     // 16KB over usm+vsm (ptr|comp<<16)

    __shared__ double sdbl[16];
    __shared__ unsigned smax4[16];
    __shared__ float sMf;
    __shared__ unsigned mTot;
    __shared__ unsigned wq[16];
    __shared__ unsigned nrS, ncS;
    __shared__ float redA[16], redB[16];
    __shared__ unsigned mvf[16];

    const int tid = threadIdx.x, lane = tid & 63, wv = tid >> 6;

    // ---------- A: reduce ----------
    {
        double s = 0.0; unsigned mk = 0u;
        #pragma unroll
        for (int t = 0; t < 4; ++t) {
            int i = tid + (t << 10);
            s += (double)rowsum[i];
            unsigned k = rowmaxk[i];
            mk = (k > mk) ? k : mk;
        }
        for (int o = 1; o < 64; o <<= 1) {
            s += __shfl_xor(s, o);
            unsigned om = __shfl_xor(mk, o);
            mk = (om > mk) ? om : mk;
        }
        if (lane == 0) { sdbl[wv] = s; smax4[wv] = mk; }
        if (tid == 0) mTot = 0u;
    }
    __syncthreads();
    if (tid == 0) {
        double bs = 0.0; unsigned m2 = 0u;
        #pragma unroll
        for (int w2 = 0; w2 < 16; ++w2) { bs += sdbl[w2]; m2 = max(m2, smax4[w2]); }
        *base_acc_g = bs;
        *Mkey_g = m2;
        sMf = finv(m2);
    }
    __syncthreads();
    const float M = sMf;
    const float zthr = M - CTHR;

    // ---------- B1: vectorized survivor count + col histogram ----------
    for (int i = tid; i < 4096; i += 1024) colCnt[i] = 0u;
    __syncthreads();
    {
        unsigned myTot = 0;
        #pragma unroll
        for (int i = 0; i < 4; ++i) {
            int r = (tid << 2) + i;
            const float4* tz4 = (const float4*)(top_z + (size_t)r * TOPK);
            int cnt = 0;
            #pragma unroll
            for (int q = 0; q < 8; ++q) {
                float4 t = tz4[q];
                cnt += (t.x > zthr) + (t.y > zthr) + (t.z > zthr) + (t.w > zthr);
            }
            rowCnt[r] = (unsigned short)cnt;
            myTot += (unsigned)cnt;
            const int* tj = top_idx + (size_t)r * TOPK;
            for (int k = 0; k < cnt; ++k)
                atomicAdd(&colCnt[(unsigned)tj[k]], 1u);
        }
        atomicAdd(&mTot, myTot);
    }
    __syncthreads();
    const int m = (int)mTot;
    if (tid == 0) { mcount_g[0] = (unsigned)m; meta_g[0] = (m > MCAP) ? 1u : 0u; }
    if (m > MCAP) return;

    // ---------- B2a: row scan -> rowPS (ptr|comp<<16) + aRowSC ----------
    {
        unsigned pre[4]; unsigned tsum = 0;
        #pragma unroll
        for (int i = 0; i < 4; ++i) {
            unsigned c2 = rowCnt[(tid << 2) + i];
            unsigned val = c2 | ((c2 ? 1u : 0u) << 16);
            pre[i] = tsum; tsum += val;
        }
        unsigned sc = tsum;
        for (int o = 1; o < 64; o <<= 1) {
            unsigned n2 = __shfl_up(sc, o);
            if (lane >= o) sc += n2;
        }
        if (lane == 63) wq[wv] = sc;
        __syncthreads();
        unsigned woff = 0;
        for (int w2 = 0; w2 < wv; ++w2) woff += wq[w2];
        unsigned base0 = woff + sc - tsum;
        #pragma unroll
        for (int i = 0; i < 4; ++i) {
            int r = (tid << 2) + i;
            unsigned pfx = base0 + pre[i];
            rowPS[r] = pfx;
            unsigned c2 = rowCnt[r];
            if (c2) aRowSC[pfx >> 16] = (pfx & 0xFFFFu) | (c2 << 16);
        }
        if (tid == 1023) nrS = (base0 + tsum) >> 16;
    }
    __syncthreads();
    // ---------- B2b: col scan -> colPS (12/12 packing, fill bits clear) ----------
    {
        unsigned pre[4]; unsigned tsum = 0;
        #pragma unroll
        for (int i = 0; i < 4; ++i) {
            unsigned c2 = colCnt[(tid << 2) + i];
            unsigned val = c2 | ((c2 ? 1u : 0u) << 12);
            pre[i] = tsum; tsum += val;
        }
        unsigned sc = tsum;
        for (int o = 1; o < 64; o <<= 1) {
            unsigned n2 = __shfl_up(sc, o);
            if (lane >= o) sc += n2;
        }
        if (lane == 63) wq[wv] = sc;
        __syncthreads();
        unsigned woff = 0;
        for (int w2 = 0; w2 < wv; ++w2) woff += wq[w2];
        unsigned base0 = woff + sc - tsum;
        #pragma unroll
        for (int i = 0; i < 4; ++i) {
            int j = (tid << 2) + i;
            unsigned pfx = base0 + pre[i];
            unsigned c2 = colCnt[j];
            colPS[j] = pfx;                    // fill bits (24+) are zero
            if (c2) {
                unsigned cc = pfx >> 12;
                aColSC[cc] = (pfx & 0xFFFu) | (c2 << 16);
                aColJ[cc] = (unsigned short)j;
            }
        }
        if (tid == 1023) ncS = (base0 + tsum) >> 12;
    }
    __syncthreads();
    {   // max col count guard (fill field 8 bits; conservative cap 64)
        unsigned mcc = 0;
        #pragma unroll
        for (int i = 0; i < 4; ++i) mcc = max(mcc, colCnt[(tid << 2) + i]);
        for (int o = 1; o < 64; o <<= 1) { unsigned t2 = __shfl_xor(mcc, o); mcc = max(mcc, t2); }
        if (lane == 0) smax4[wv] = mcc;
    }
    __syncthreads();
    {
        unsigned mx = 0;
        #pragma unroll
        for (int w2 = 0; w2 < 16; ++w2) mx = max(mx, smax4[w2]);
        if (tid == 0 && mx > 64u) meta_g[0] = 1u;
        if (mx > 64u) return;   // uniform
    }
    __syncthreads();   // colCnt fully consumed -> rpack overlay may be written

    // ---------- B3: fill packed CSR (fill counter lives in colPS bits 24+) ----------
    #pragma unroll
    for (int i = 0; i < 4; ++i) {
        int r = (tid << 2) + i;
        int cnt = rowCnt[r];
        if (!cnt) continue;
        unsigned rps = rowPS[r];
        unsigned rptr = rps & 0xFFFFu, rcomp = rps >> 16;
        const float* tz = top_z + (size_t)r * TOPK;
        const int* tj = top_idx + (size_t)r * TOPK;
        for (int k = 0; k < cnt; ++k) {
            float c = fmaxf(M - tz[k], 0.0f);
            float e = expf(-(c / OT_EPS_F));
            unsigned vb = __float_as_uint(e - FLOORK);
            unsigned j = (unsigned)tj[k];
            unsigned old = atomicAdd(&colPS[j], 1u << 24);
            unsigned cptr = old & 0xFFFu, ccomp = (old >> 12) & 0xFFFu, prior = old >> 24;
            rpack[rptr + (unsigned)k] = (unsigned long long)vb | ((unsigned long long)ccomp << 32);
            cpack[cptr + prior]       = (unsigned long long)vb | ((unsigned long long)rcomp << 32);
        }
    }
    __syncthreads();
    // ---------- B4: init scaling tables (frees rowPS overlay of usm/vsm) ----------
    for (int i = tid; i < 2048; i += 1024) { usm[i] = 1.0f; vsm[i] = 1.0f; }

    // ---------- preload run metadata to registers ----------
    const int nr = (int)nrS, nc = (int)ncS;
    unsigned rme[2], cme[2];
    #pragma unroll
    for (int s = 0; s < 2; ++s) {
        int i = tid + (s << 10);
        rme[s] = (i < nr) ? aRowSC[i] : 0u;
        cme[s] = (i < nc) ? aColSC[i] : 0u;
    }
    __syncthreads();

    // ---------- D: 16-wave direct-gather Sinkhorn, 2 barriers/iter ----------
    float u0 = 1.0f, v0 = 1.0f;
    float SvA = (float)nc;
    for (int it = 0; it < 30; ++it) {
        const float bgu = FLOORK * ((float)(B - nc) * v0 + SvA) + 1e-8f;
        const float u0n = AMASS * rcpf_(bgu);
        float SuP = 0.0f;
        #pragma unroll
        for (int s = 0; s < 2; ++s) {
            unsigned me = rme[s];
            unsigned ct = me >> 16;
            if (ct) {
                unsigned st = me & 0xFFFFu;
                float ss = 0.0f;
                for (unsigned k = 0; k < ct; ++k) {
                    unsigned long long wd = rpack[st + k];
                    ss += __uint_as_float((unsigned)wd) * vsm[(unsigned)(wd >> 32)];
                }
                float u = AMASS * rcpf_(bgu + ss);
                usm[tid + (s << 10)] = u;
                SuP += u;
            }
        }
        SuP = wsum64(SuP);
        if (lane == 0) redA[wv] = SuP;
        __syncthreads();                                   // (1) usm + redA ready
        float Su = 0.0f;
        #pragma unroll
        for (int w2 = 0; w2 < 16; ++w2) Su += redA[w2];
        const float bgv = FLOORK * ((float)(B - nr) * u0n + Su) + 1e-8f;
        const float v0n = AMASS * rcpf_(bgv);
        float SvP = 0.0f; bool moved = false;
        #pragma unroll
        for (int s = 0; s < 2; ++s) {
            unsigned me = cme[s];
            unsigned ct = me >> 16;
            if (ct) {
                unsigned st = me & 0xFFFFu;
                float ss = 0.0f;
                for (unsigned k = 0; k < ct; ++k) {
                    unsigned long long wd = cpack[st + k];
                    ss += __uint_as_float((unsigned)wd) * usm[(unsigned)(wd >> 32)];
                }
                float vn = AMASS * rcpf_(bgv + ss);
                int i2 = tid + (s << 10);
                float vold = vsm[i2];
                if (fabsf(vn - vold) > EPS_L * vold) moved = true;
                vsm[i2] = vn;
                SvP += vn;
            }
        }
        SvP = wsum64(SvP);
        if (lane == 0) { redB[wv] = SvP; mvf[wv] = (__ballot(moved) != 0ull) ? 1u : 0u; }
        __syncthreads();                                   // (2) vsm + redB + mvf ready
        float Sv2 = 0.0f; unsigned mvAll = 0u;
        #pragma unroll
        for (int w2 = 0; w2 < 16; ++w2) { Sv2 += redB[w2]; mvAll |= mvf[w2]; }
        SvA = Sv2;
        const bool conv = (mvAll == 0u) &&
                          (fabsf(v0n - v0) <= EPS_L * v0) &&
                          (fabsf(u0n - u0) <= EPS_L * u0);
        u0 = u0n; v0 = v0n;
        if (conv) break;   // uniform
    }

    // ---------- epilogue: fill background v0, overwrite active cols ----------
    {
        float4* vo4 = (float4*)vout;
        const float4 fill = make_float4(v0, v0, v0, v0);
        for (int t2 = tid; t2 < 1024; t2 += 1024) vo4[t2] = fill;
        // grid-stride above covers all 1024 float4 in one pass (tid 0..1023)
        __syncthreads();
        for (int i = tid; i < nc; i += 1024)
            vout[aColJ[i]] = vsm[i];
    }
}

// ---------------------------------------------------------------------------
// k4_fb: list-free global Sinkhorn fallback (meta[0]==1 only). Correctness path.
// ---------------------------------------------------------------------------
__global__ __launch_bounds__(256) void k4_fb(const unsigned int* __restrict__ meta,
                                             const unsigned int* __restrict__ Mkey,
                                             const float* __restrict__ top_z,
                                             const int* __restrict__ top_idx,
                                             float* __restrict__ evals,
                                             float* __restrict__ gv,
                                             float* __restrict__ ga,
                                             float* __restrict__ gb,
                                             float* __restrict__ vout) {
    if (meta[0] == 0u) return;
    __shared__ float red[4];
    __shared__ float bc;
    const int tid = threadIdx.x, lane = tid & 63, wv = tid >> 6;
    const float M = finv(Mkey[0]);

    for (int c = tid; c < B * TOPK; c += 256) {
        float cc = fmaxf(M - top_z[c], 0.0f);
        float e = 0.0f;
        if (cc < CPRE) {
            float t = expf(-(cc / OT_EPS_F));
            if (t > FLOORK) e = t - FLOORK;
        }
        evals[c] = e;
    }
    for (int i = tid; i < B; i += 256) gv[i] = 1.0f;
    __syncthreads();

    for (int it = 0; it < 30; ++it) {
        float s = 0.0f;
        for (int i = tid; i < B; i += 256) { s += gv[i]; ga[i] = 0.0f; }
        for (int o = 1; o < 64; o <<= 1) s += __shfl_xor(s, o);
        if (lane == 0) red[wv] = s;
        __syncthreads();
        if (tid == 0) bc = red[0] + red[1] + red[2] + red[3];
        __syncthreads();
        const float bgu = FLOORK * bc + 1e-8f;
        for (int c = tid; c < B * TOPK; c += 256) {
            float a = evals[c];
            if (a > 0.0f) atomicAdd(&ga[c >> 5], a * gv[top_idx[c]]);
        }
        __syncthreads();
        float su = 0.0f;
        for (int i = tid; i < B; i += 256) { su += AMASS / (bgu + ga[i]); gb[i] = 0.0f; }
        for (int o = 1; o < 64; o <<= 1) su += __shfl_xor(su, o);
        if (lane == 0) red[wv] = su;
        __syncthreads();
        if (tid == 0) bc = red[0] + red[1] + red[2] + red[3];
        __syncthreads();
        const float bgv = FLOORK * bc + 1e-8f;
        for (int c = tid; c < B * TOPK; c += 256) {
            float a = evals[c];
            if (a > 0.0f) {
                float u = AMASS / (bgu + ga[c >> 5]);
                atomicAdd(&gb[top_idx[c]], a * u);
            }
        }
        __syncthreads();
        for (int i = tid; i < B; i += 256) gv[i] = AMASS / (bgv + gb[i]);
        __syncthreads();
    }
    for (int i = tid; i < B; i += 256) vout[i] = gv[i];
}

// ---------------------------------------------------------------------------
// k5: per row: weights = K*v (u cancels), synthetic negative, normalize,
// dot with text row.
// ---------------------------------------------------------------------------
__global__ __launch_bounds__(256) void k5_synth(const int* __restrict__ top_idx,
                                                const float* __restrict__ top_z,
                                                const unsigned int* __restrict__ Mkey,
                                                const float* __restrict__ v,
                                                const float* __restrict__ image,
                                                const float* __restrict__ text,
                                                float* __restrict__ synth_sim) {
    __shared__ float sw[TOPK];
    __shared__ int   sj[TOPK];
    __shared__ float red[4];
    __shared__ float bcast;

    const int row = blockIdx.x, tid = threadIdx.x;
    const int wid = tid >> 6, lane = tid & 63;
    const float M = finv(Mkey[0]);

    if (tid < 64) {
        float wt = 0.0f;
        if (tid < TOPK) {
            int j = top_idx[(size_t)row * TOPK + tid];
            float z = top_z[(size_t)row * TOPK + tid];
            float c = fmaxf(M - z, 0.0f);
            float K = fmaxf(expf(-(c / OT_EPS_F)), FLOORK);
            wt = K * v[j];
            sj[tid] = j;
            sw[tid] = wt;
        }
        float s = wt;
        for (int off = 32; off; off >>= 1) s += __shfl_down(s, off);
        if (tid == 0) bcast = fmaxf(s, 1e-8f);
    }
    __syncthreads();
    if (tid < TOPK) sw[tid] = sw[tid] / bcast;
    __syncthreads();

    float s0 = 0.0f, s1 = 0.0f;
    for (int t = 0; t < TOPK; ++t) {
        float wv2 = sw[t];
        const float* img = image + (size_t)sj[t] * D;
        s0 += wv2 * img[tid];
        s1 += wv2 * img[tid + 256];
    }
    float nn = s0 * s0 + s1 * s1;
    for (int off = 32; off; off >>= 1) nn += __shfl_down(nn, off);
    if (lane == 0) red[wid] = nn;
    __syncthreads();
    float norm2 = red[0] + red[1] + red[2] + red[3];
    float den = sqrtf(norm2) + 1e-8f;
    float p = (s0 / den) * text[(size_t)row * D + tid] +
              (s1 / den) * text[(size_t)row * D + tid + 256];
    __syncthreads();
    for (int off = 32; off; off >>= 1) p += __shfl_down(p, off);
    if (lane == 0) red[wid] = p;
    __syncthreads();
    if (tid == 0) synth_sim[row] = red[0] + red[1] + red[2] + red[3];
}

// ---------------------------------------------------------------------------
// k78: median of ratio via radix select, then gate + final combine.
// ---------------------------------------------------------------------------
__global__ __launch_bounds__(256) void k78_final(const float* __restrict__ ratio,
                                                 const float* __restrict__ synth_sim,
                                                 const double* __restrict__ base_acc,
                                                 float* __restrict__ out) {
    __shared__ unsigned int skey[B];
    __shared__ unsigned int histm[4 * 257 + 4];
    __shared__ unsigned int selb, selk;
    __shared__ double rs[4];
    __shared__ float rg[4];

    const int tid = threadIdx.x, wid = tid >> 6, lane = tid & 63;

    #pragma unroll
    for (int t = 0; t < 16; ++t) {
        int c = tid + (t << 8);
        skey[c] = fkey(ratio[c]);
    }
    __syncthreads();

    unsigned int prefix = 0, kneed = 2048;
    for (int r = 0; r < 4; ++r) {
        for (int i = tid; i < 4 * 257 + 4; i += 256) histm[i] = 0;
        __syncthreads();
        const int shift = 24 - 8 * r;
        unsigned int cb = 0xFFFFFFFFu, cc = 0;
        #pragma unroll
        for (int t = 0; t < 16; ++t) {
            unsigned int kx = skey[tid + (t << 8)];
            bool part = (r == 0) || ((kx >> (32 - 8 * r)) == prefix);
            if (part) {
                unsigned int bin = (kx >> shift) & 255u;
                if (bin == cb) ++cc;
                else {
                    if (cc) atomicAdd(&histm[wid * 257 + cb], cc);
                    cb = bin; cc = 1;
                }
            }
        }
        if (cc) atomicAdd(&histm[wid * 257 + cb], cc);
        __syncthreads();
        unsigned int h = histm[tid] + histm[257 + tid] + histm[514 + tid] + histm[771 + tid];
        unsigned int s = h;
        for (int off = 1; off < 64; off <<= 1) {
            unsigned int o = __shfl_down(s, off);
            if (lane + off < 64) s += o;
        }
        if (lane == 0) histm[1028 + wid] = s;
        __syncthreads();
        unsigned int coarse = 0;
        for (int w = wid + 1; w < 4; ++w) coarse += histm[1028 + w];
        unsigned int incl = s + coarse, strict = incl - h;
        if (strict < kneed && kneed <= incl) { selb = (unsigned int)tid; selk = kneed - strict; }
        __syncthreads();
        prefix = (prefix << 8) | selb;
        kneed = selk;
        __syncthreads();
    }
    const unsigned int KA = prefix;
    const unsigned int g = 2048u - kneed;

    unsigned int ec = 0, mb = 0;
    #pragma unroll
    for (int t = 0; t < 16; ++t) {
        unsigned int kx = skey[tid + (t << 8)];
        if (kx == KA) ++ec;
        else if (kx < KA && kx > mb) mb = kx;
    }
    for (int off = 1; off < 64; off <<= 1) {
        ec += __shfl_xor(ec, off);
        unsigned int o = __shfl_xor(mb, off);
        mb = (o > mb) ? o : mb;
    }
    __syncthreads();
    if (lane == 0) { histm[wid] = ec; histm[8 + wid] = mb; }
    __syncthreads();
    unsigned int E  = histm[0] + histm[1] + histm[2] + histm[3];
    unsigned int MB = max(max(histm[8], histm[9]), max(histm[10], histm[11]));
    unsigned int KB = (g + E >= 2049u) ? KA : MB;
    const float scale = 0.5f * (finv(KA) + finv(KB));

    double lsd = 0.0; float gs = 0.0f;
    #pragma unroll
    for (int t = 0; t < 16; ++t) {
        float sl = scale * synth_sim[tid + (t << 8)];
        if (sl > -0.05f) { gs += 1.0f; lsd += (double)softplusf(sl); }
    }
    for (int off = 1; off < 64; off <<= 1) {
        lsd += __shfl_xor(lsd, off);
        gs  += __shfl_xor(gs, off);
    }
    if (lane == 0) { rs[wid] = lsd; rg[wid] = gs; }
    __syncthreads();
    if (tid == 0) {
        double L = rs[0] + rs[1] + rs[2] + rs[3];
        float  G = rg[0] + rg[1] + rg[2] + rg[3];
        double base = base_acc[0] / ((double)B * (double)B);
        double synth = (G > 0.0f) ? (L / ((double)G + 1e-8)) : 0.0;
        out[0] = (float)(base + 0.5 * synth);
    }
}

extern "C" void kernel_launch(void* const* d_in, const int* in_sizes, int n_in,
                              void* d_out, int out_size, void* d_ws, size_t ws_size,
                              hipStream_t stream) {
    const float* logits = (const float*)d_in[0];
    const float* text   = (const float*)d_in[1];
    const float* image  = (const float*)d_in[2];
    const float* bias   = (const float*)d_in[3];

    char* ws = (char*)d_ws;
    double*       base_acc = (double*)(ws + 0);
    unsigned int* mcount   = (unsigned int*)(ws + 8);
    unsigned int* Mkey     = (unsigned int*)(ws + 12);
    unsigned int* meta     = (unsigned int*)(ws + 16);
    unsigned int* flags    = (unsigned int*)(ws + 64);            // 16 KB
    float*        rowsum   = (float*)(ws + 64 + 16384);
    unsigned int* rowmaxk  = (unsigned int*)(rowsum + B);
    float*        v        = (float*)(rowmaxk + B);
    float*        sim      = v + B;
    float*        ratio    = sim + B;
    float*        gv       = ratio + B;
    float*        ga       = gv + B;
    float*        gb       = ga + B;
    int*          top_idx  = (int*)(gb + B);
    float*        top_z    = (float*)(top_idx + (size_t)B * TOPK);
    float*        evals    = (float*)(top_z + (size_t)B * TOPK);

    // zero: header + flags (k1_fallback gating)
    (void)hipMemsetAsync(ws, 0, 64 + 16384, stream);

    k1_row     <<<B / 4, 256, 0, stream>>>(logits, text, image, bias, rowsum, rowmaxk,
                                           top_idx, top_z, ratio, flags);
    k1_fallback<<<B, 256, 0, stream>>>(logits, bias, flags, top_idx, top_z);
    kmid       <<<1, 1024, 0, stream>>>(rowsum, rowmaxk, top_z, top_idx, Mkey, base_acc,
                                        mcount, meta, v);
    k4_fb      <<<1, 256, 0, stream>>>(meta, Mkey, top_z, top_idx, evals, gv, ga, gb, v);
    k5_synth   <<<B, 256, 0, stream>>>(top_idx, top_z, Mkey, v, image, text, sim);
    k78_final  <<<1, 256, 0, stream>>>(ratio, sim, base_acc, (float*)d_out);
}

// Round 20
// 143.776 us; speedup vs baseline: 2.5123x; 1.0759x over previous
//
#include <hip/hip_runtime.h>
#include <math.h>

#define B 4096
#define D 512
#define TOPK 32
#define MCAP 2048

constexpr float OT_EPS_F = 0.05f;
constexpr float FLOORK   = 1e-12f;
constexpr float AMASS    = 1.0f / 4096.0f;   // exact 2^-12
constexpr float TAU      = 1.8f;             // k1 candidate prefilter threshold
constexpr float EPS_L    = 1e-4f;            // loop convergence tolerance (bounded drift)
constexpr float CPRE     = 1.45f;            // conservative cost prefilter (fallback path)
constexpr float CTHR     = 1.3815510f;       // analytic: e>1e-12 <=> c < 0.05*ln(1e12)

// fast softplus via HW transcendentals (v_exp_f32 / v_log_f32), ~1e-7 abs err
__device__ __forceinline__ float softplusf(float x) {
    return fmaxf(x, 0.0f) + __logf(1.0f + __expf(-fabsf(x)));
}
__device__ __forceinline__ unsigned int fkey(float f) {
    unsigned int x = __float_as_uint(f);
    return x ^ ((x & 0x80000000u) ? 0xFFFFFFFFu : 0x80000000u);
}
__device__ __forceinline__ float finv(unsigned int k) {
    unsigned int x = (k & 0x80000000u) ? (k ^ 0x80000000u) : ~k;
    return __uint_as_float(x);
}
__device__ __forceinline__ float rcpf_(float x) { return __builtin_amdgcn_rcpf(x); }
__device__ __forceinline__ void lgkm0() {
    asm volatile("s_waitcnt lgkmcnt(0)" ::: "memory");
    __builtin_amdgcn_sched_barrier(0);
}
#define DPPADD(x, ctrl) ((x) + __int_as_float(__builtin_amdgcn_update_dpp(0, __float_as_int(x), (ctrl), 0xf, 0xf, false)))
__device__ __forceinline__ float wsum64(float x) {
    x = DPPADD(x, 0x111);
    x = DPPADD(x, 0x112);
    x = DPPADD(x, 0x114);
    x = DPPADD(x, 0x118);
    x = DPPADD(x, 0x142);
    x = DPPADD(x, 0x143);
    return __int_as_float(__builtin_amdgcn_readlane(__float_as_int(x), 63));
}

// ---------------------------------------------------------------------------
// k1: wave-per-row (4 rows / 256-block). Unchanged.
// ---------------------------------------------------------------------------
__global__ __launch_bounds__(256) void k1_row(const float* __restrict__ logits,
                                              const float* __restrict__ text,
                                              const float* __restrict__ image,
                                              const float* __restrict__ bias_p,
                                              float* __restrict__ rowsum,
                                              unsigned int* __restrict__ rowmaxk,
                                              int* __restrict__ top_idx,
                                              float* __restrict__ top_z,
                                              float* __restrict__ ratio,
                                              unsigned int* __restrict__ flags) {
    __shared__ unsigned int candk[4][128];
    __shared__ unsigned int candi[4][128];
    __shared__ unsigned int wcnt[4];
    __shared__ unsigned int skk[4][32];
    __shared__ unsigned int ski[4][32];

    const int tid = threadIdx.x, w = tid >> 6, lane = tid & 63;
    const int row = (blockIdx.x << 2) + w;
    const float bias = bias_p[0];
    const float* lr = logits + (size_t)row * B;
    const float4* lr4 = (const float4*)lr;

    if (lane == 0) wcnt[w] = 0;
    candk[w][lane] = 0; candk[w][lane + 64] = 0;

    float lsum = 0.0f, lmax = -INFINITY;
    bool ovf = false;

#define K1ELEM(ZV, CC) do {                                                   \
        float z_ = (ZV) + bias;                                               \
        bool dg_ = ((CC) == row);                                             \
        float sp_ = softplusf(z_);                                            \
        lsum += dg_ ? (sp_ - z_) : sp_;                                       \
        float zm_ = dg_ ? -INFINITY : z_;                                     \
        lmax = fmaxf(lmax, zm_);                                              \
        if (zm_ > TAU) {                                                      \
            unsigned int p_ = atomicAdd(&wcnt[w], 1u);                        \
            if (p_ < 128u) { candk[w][p_] = __float_as_uint(z_);              \
                             candi[w][p_] = (unsigned int)(CC); }             \
            else ovf = true;                                                  \
        } } while (0)

    #pragma unroll
    for (int t = 0; t < 16; ++t) {
        float4 z4 = lr4[lane + (t << 6)];
        int cb = (lane << 2) + (t << 8);
        K1ELEM(z4.x, cb);
        K1ELEM(z4.y, cb + 1);
        K1ELEM(z4.z, cb + 2);
        K1ELEM(z4.w, cb + 3);
    }
#undef K1ELEM
    __syncthreads();

    for (int o = 1; o < 64; o <<= 1) {
        lsum += __shfl_xor(lsum, o);
        lmax = fmaxf(lmax, __shfl_xor(lmax, o));
    }
    if (lane == 0) { rowsum[row] = lsum; rowmaxk[row] = fkey(lmax); }

    const unsigned int n = wcnt[w];
    bool fb = (n < (unsigned)TOPK) || (n > 128u) || (__ballot(ovf) != 0ull);

    const unsigned int c0k = candk[w][lane], c1k = candk[w][lane + 64];
    const unsigned int i0  = candi[w][lane], i1  = candi[w][lane + 64];

    if (!fb) {
        unsigned int K = 0u;
        for (int b = 31; b >= 0; --b) {
            unsigned int tr = K | (1u << b);
            int cnt = __popcll(__ballot(c0k >= tr)) + __popcll(__ballot(c1k >= tr));
            if (cnt >= TOPK) K = tr;
        }
        unsigned long long m0g = __ballot(c0k > K), m1g = __ballot(c1k > K);
        unsigned long long m0e = __ballot(c0k == K), m1e = __ballot(c1k == K);
        int cnt_gt = __popcll(m0g) + __popcll(m1g);
        int kneed  = TOPK - cnt_gt;
        int eqc    = __popcll(m0e) + __popcll(m1e);
        if (eqc != kneed) {
            fb = true;   // boundary ties -> exact fallback
        } else {
            unsigned long long lmlt = (1ull << lane) - 1ull;
            int r0 = __popcll(m0g & lmlt);
            if (c0k > K) { skk[w][r0] = c0k; ski[w][r0] = i0; }
            int r1 = __popcll(m0g) + __popcll(m1g & lmlt);
            if (c1k > K) { skk[w][r1] = c1k; ski[w][r1] = i1; }
            int e0 = cnt_gt + __popcll(m0e & lmlt);
            if (c0k == K) { skk[w][e0] = c0k; ski[w][e0] = i0; }
            int e1 = cnt_gt + __popcll(m0e) + __popcll(m1e & lmlt);
            if (c1k == K) { skk[w][e1] = c1k; ski[w][e1] = i1; }
            lgkm0();   // in-wave LDS ordering
            if (lane < 32) {
                unsigned int my = skk[w][lane], mi = ski[w][lane];
                int rk = 0;
                #pragma unroll
                for (int k = 0; k < 32; ++k) {
                    unsigned int ok = skk[w][k];
                    rk += (int)((ok > my) || (ok == my && k < lane));
                }
                size_t rb = (size_t)row * TOPK;
                top_idx[rb + rk] = (int)mi;
                top_z [rb + rk] = __uint_as_float(my);
            }
        }
    }
    if (fb && lane == 0) flags[row] = 1u;

    // ---- fused ratio sample ----
    unsigned int hh = (unsigned int)row * 2654435761u;
    int j = (int)(((unsigned int)row + 1u + (hh % 4095u)) & 4095u);   // j != row
    const float4* tr4 = (const float4*)(text + (size_t)row * D);
    const float4* ir4 = (const float4*)(image + (size_t)j * D);
    float4 a0 = tr4[lane], b0 = ir4[lane];
    float4 a1 = tr4[lane + 64], b1 = ir4[lane + 64];
    float s3 = a0.x * b0.x + a0.y * b0.y + a0.z * b0.z + a0.w * b0.w
             + a1.x * b1.x + a1.y * b1.y + a1.z * b1.z + a1.w * b1.w;
    for (int o = 1; o < 64; o <<= 1) s3 += __shfl_xor(s3, o);
    if (lane == 0) ratio[row] = lr[j] / (s3 + 1e-8f);
}

// ---------------------------------------------------------------------------
// k1f: exact fallback for flagged rows. Normally no-op. Unchanged.
// ---------------------------------------------------------------------------
__global__ __launch_bounds__(256) void k1_fallback(const float* __restrict__ logits,
                                                   const float* __restrict__ bias_p,
                                                   const unsigned int* __restrict__ flags,
                                                   int* __restrict__ top_idx,
                                                   float* __restrict__ top_z) {
    const int row = blockIdx.x;
    if (flags[row] == 0u) return;

    __shared__ unsigned int skey[B];
    __shared__ unsigned int histm[4 * 257 + 4];
    __shared__ unsigned int selb, selk;
    __shared__ int cnt_gt, cnt_eq;
    __shared__ int eqi[64];
    __shared__ unsigned int sk2[32], si2[32];

    const int tid = threadIdx.x, wid = tid >> 6, lane = tid & 63;
    const float bias = bias_p[0];
    const float* lr = logits + (size_t)row * B;

    #pragma unroll
    for (int t = 0; t < 16; ++t) {
        int c = tid + (t << 8);
        float z = lr[c] + bias;
        skey[c] = fkey((c == row) ? -INFINITY : z);
    }
    if (tid == 0) { cnt_gt = 0; cnt_eq = 0; }
    __syncthreads();

    unsigned int prefix = 0, kneed = TOPK;
    for (int r = 0; r < 4; ++r) {
        for (int i = tid; i < 4 * 257 + 4; i += 256) histm[i] = 0;
        __syncthreads();
        const int shift = 24 - 8 * r;
        #pragma unroll
        for (int t = 0; t < 16; ++t) {
            int c = tid + (t << 8);
            unsigned int kx = skey[c];
            bool part = (r == 0) || ((kx >> (32 - 8 * r)) == prefix);
            if (part) atomicAdd(&histm[wid * 257 + ((kx >> shift) & 255u)], 1u);
        }
        __syncthreads();
        unsigned int h = histm[tid] + histm[257 + tid] + histm[514 + tid] + histm[771 + tid];
        unsigned int s = h;
        for (int off = 1; off < 64; off <<= 1) {
            unsigned int o = __shfl_down(s, off);
            if (lane + off < 64) s += o;
        }
        if (lane == 0) histm[1028 + wid] = s;
        __syncthreads();
        unsigned int coarse = 0;
        for (int ww = wid + 1; ww < 4; ++ww) coarse += histm[1028 + ww];
        unsigned int incl = s + coarse, strict = incl - h;
        if (strict < kneed && kneed <= incl) { selb = (unsigned int)tid; selk = kneed - strict; }
        __syncthreads();
        prefix = (prefix << 8) | selb;
        kneed = selk;
        __syncthreads();
    }
    const unsigned int K32 = prefix;

    #pragma unroll
    for (int t = 0; t < 16; ++t) {
        int c = tid + (t << 8);
        unsigned int kx = skey[c];
        if (kx > K32) {
            int p = atomicAdd(&cnt_gt, 1);
            top_idx[(size_t)row * TOPK + p] = c;
            top_z [(size_t)row * TOPK + p] = finv(kx);
        } else if (kx == K32) {
            int p = atomicAdd(&cnt_eq, 1);
            if (p < 64) eqi[p] = c;
        }
    }
    __syncthreads();
    if (tid == 0) {
        int q = (int)kneed, base = cnt_gt, E = cnt_eq;
        float zv = finv(K32);
        if (E <= 64) {
            for (int s2 = 0; s2 < q; ++s2) {
                int best = 0x7FFFFFFF, bp = 0;
                for (int e = 0; e < E; ++e) { int ix = eqi[e]; if (ix < best) { best = ix; bp = e; } }
                eqi[bp] = 0x7FFFFFFF;
                top_idx[(size_t)row * TOPK + base + s2] = best;
                top_z [(size_t)row * TOPK + base + s2] = zv;
            }
        } else {
            int taken = 0;
            for (int c = 0; c < B && taken < q; ++c)
                if (skey[c] == K32) {
                    top_idx[(size_t)row * TOPK + base + taken] = c;
                    top_z [(size_t)row * TOPK + base + taken] = zv;
                    ++taken;
                }
        }
    }
    __syncthreads();
    if (tid < 32) {
        sk2[tid] = fkey(top_z[(size_t)row * TOPK + tid]);
        si2[tid] = (unsigned int)top_idx[(size_t)row * TOPK + tid];
    }
    __syncthreads();
    if (tid < 32) {
        unsigned int my = sk2[tid], mi = si2[tid];
        int rk = 0;
        #pragma unroll
        for (int k = 0; k < 32; ++k) {
            unsigned int ok = sk2[k];
            rk += (int)((ok > my) || (ok == my && k < tid));
        }
        top_idx[(size_t)row * TOPK + rk] = (int)mi;
        top_z [(size_t)row * TOPK + rk] = finv(my);
    }
}

// ---------------------------------------------------------------------------
// kmid: grid=2. Block 0: fused reduce + CSR build + 16-wave Sinkhorn (round-19
// structure). Block 1: ratio-median radix select (rides under block 0's
// latency shadow on another CU), writes scale_g.
// ---------------------------------------------------------------------------
__global__ __launch_bounds__(1024) void kmid(const float* __restrict__ rowsum,
                                             const unsigned int* __restrict__ rowmaxk,
                                             const float* __restrict__ top_z,
                                             const int* __restrict__ top_idx,
                                             const float* __restrict__ ratio,
                                             unsigned int* __restrict__ Mkey_g,
                                             double* __restrict__ base_acc_g,
                                             unsigned int* __restrict__ mcount_g,
                                             unsigned int* __restrict__ meta_g,
                                             float* __restrict__ scale_g,
                                             float* __restrict__ vout) {
    __shared__ __align__(16) unsigned char SB[94208];
    const int tid = threadIdx.x, lane = tid & 63, wv = tid >> 6;

    if (blockIdx.x == 1) {
        // ================= block 1: median of ratio (rank 2048/2049) ========
        unsigned* skey = (unsigned*)(SB);                 // [4096] 16KB
        unsigned* hist = (unsigned*)(SB + 16384);         // [16*257+16] ~16.5KB
        __shared__ unsigned selbM, selkM;
        __shared__ unsigned ecw[16], mbw[16];

        for (int c = tid; c < B; c += 1024) skey[c] = fkey(ratio[c]);
        __syncthreads();

        unsigned prefix = 0, kneed = 2048;
        for (int r = 0; r < 4; ++r) {
            for (int i = tid; i < 16 * 257 + 16; i += 1024) hist[i] = 0;
            __syncthreads();
            const int shift = 24 - 8 * r;
            #pragma unroll
            for (int t = 0; t < 4; ++t) {
                unsigned kx = skey[tid + (t << 10)];
                bool part = (r == 0) || ((kx >> (32 - 8 * r)) == prefix);
                if (part) atomicAdd(&hist[wv * 257 + ((kx >> shift) & 255u)], 1u);
            }
            __syncthreads();
            unsigned h = 0, s = 0;
            if (tid < 256) {
                for (int w2 = 0; w2 < 16; ++w2) h += hist[w2 * 257 + tid];
                s = h;
                for (int off = 1; off < 64; off <<= 1) {
                    unsigned o = __shfl_down(s, off);
                    if (lane + off < 64) s += o;
                }
                if (lane == 0) hist[16 * 257 + wv] = s;   // wv in 0..3 here
            }
            __syncthreads();
            if (tid < 256) {
                unsigned coarse = 0;
                for (int w2 = wv + 1; w2 < 4; ++w2) coarse += hist[16 * 257 + w2];
                unsigned incl = s + coarse, strict = incl - h;
                if (strict < kneed && kneed <= incl) { selbM = (unsigned)tid; selkM = kneed - strict; }
            }
            __syncthreads();
            prefix = (prefix << 8) | selbM;
            kneed = selkM;
            __syncthreads();
        }
        const unsigned KA = prefix;
        const unsigned g = 2048u - kneed;

        unsigned ec = 0, mb = 0;
        #pragma unroll
        for (int t = 0; t < 4; ++t) {
            unsigned kx = skey[tid + (t << 10)];
            if (kx == KA) ++ec;
            else if (kx < KA && kx > mb) mb = kx;
        }
        for (int off = 1; off < 64; off <<= 1) {
            ec += __shfl_xor(ec, off);
            unsigned o = __shfl_xor(mb, off);
            mb = (o > mb) ? o : mb;
        }
        if (lane == 0) { ecw[wv] = ec; mbw[wv] = mb; }
        __syncthreads();
        if (tid == 0) {
            unsigned E = 0, MB = 0;
            #pragma unroll
            for (int w2 = 0; w2 < 16; ++w2) { E += ecw[w2]; MB = max(MB, mbw[w2]); }
            unsigned KB = (g + E >= 2049u) ? KA : MB;
            scale_g[0] = 0.5f * (finv(KA) + finv(KB));
        }
        return;
    }

    // ================= block 0: Sinkhorn (round-19 structure) ===============
    unsigned long long* rpack = (unsigned long long*)(SB + 0);      // [2048] 16KB
    unsigned long long* cpack = (unsigned long long*)(SB + 16384);  // [2048] 16KB
    float*  usm      = (float*)(SB + 32768);                        // [2048] 8KB
    float*  vsm      = (float*)(SB + 40960);                        // [2048] 8KB
    unsigned* aRowSC = (unsigned*)(SB + 49152);                     // [2048] 8KB
    unsigned* aColSC = (unsigned*)(SB + 57344);                     // [2048] 8KB
    unsigned short* aColJ = (unsigned short*)(SB + 65536);          // [2048] 4KB
    unsigned* colPS  = (unsigned*)(SB + 69632);                     // [4096] 16KB
    unsigned short* rowCnt = (unsigned short*)(SB + 86016);         // [4096] 8KB
    unsigned* colCnt = (unsigned*)(SB + 0);                         // overlay
    unsigned* rowPS  = (unsigned*)(SB + 32768);                     // overlay

    __shared__ double sdbl[16];
    __shared__ unsigned smax4[16];
    __shared__ float sMf;
    __shared__ unsigned mTot;
    __shared__ unsigned wq[16];
    __shared__ unsigned nrS, ncS;
    __shared__ float redA[16], redB[16];
    __shared__ unsigned mvf[16];

    // ---------- A: reduce ----------
    {
        double s = 0.0; unsigned mk = 0u;
        #pragma unroll
        for (int t = 0; t < 4; ++t) {
            int i = tid + (t << 10);
            s += (double)rowsum[i];
            unsigned k = rowmaxk[i];
            mk = (k > mk) ? k : mk;
        }
        for (int o = 1; o < 64; o <<= 1) {
            s += __shfl_xor(s, o);
            unsigned om = __shfl_xor(mk, o);
            mk = (om > mk) ? om : mk;
        }
        if (lane == 0) { sdbl[wv] = s; smax4[wv] = mk; }
        if (tid == 0) mTot = 0u;
    }
    __syncthreads();
    if (tid == 0) {
        double bs = 0.0; unsigned m2 = 0u;
        #pragma unroll
        for (int w2 = 0; w2 < 16; ++w2) { bs += sdbl[w2]; m2 = max(m2, smax4[w2]); }
        *base_acc_g = bs;
        *Mkey_g = m2;
        sMf = finv(m2);
    }
    __syncthreads();
    const float M = sMf;
    const float zthr = M - CTHR;

    // ---------- B1 ----------
    for (int i = tid; i < 4096; i += 1024) colCnt[i] = 0u;
    __syncthreads();
    {
        unsigned myTot = 0;
        #pragma unroll
        for (int i = 0; i < 4; ++i) {
            int r = (tid << 2) + i;
            const float4* tz4 = (const float4*)(top_z + (size_t)r * TOPK);
            int cnt = 0;
            #pragma unroll
            for (int q = 0; q < 8; ++q) {
                float4 t = tz4[q];
                cnt += (t.x > zthr) + (t.y > zthr) + (t.z > zthr) + (t.w > zthr);
            }
            rowCnt[r] = (unsigned short)cnt;
            myTot += (unsigned)cnt;
            const int* tj = top_idx + (size_t)r * TOPK;
            for (int k = 0; k < cnt; ++k)
                atomicAdd(&colCnt[(unsigned)tj[k]], 1u);
        }
        atomicAdd(&mTot, myTot);
    }
    __syncthreads();
    const int m = (int)mTot;
    if (tid == 0) { mcount_g[0] = (unsigned)m; meta_g[0] = (m > MCAP) ? 1u : 0u; }
    if (m > MCAP) return;

    // ---------- B2a ----------
    {
        unsigned pre[4]; unsigned tsum = 0;
        #pragma unroll
        for (int i = 0; i < 4; ++i) {
            unsigned c2 = rowCnt[(tid << 2) + i];
            unsigned val = c2 | ((c2 ? 1u : 0u) << 16);
            pre[i] = tsum; tsum += val;
        }
        unsigned sc = tsum;
        for (int o = 1; o < 64; o <<= 1) {
            unsigned n2 = __shfl_up(sc, o);
            if (lane >= o) sc += n2;
        }
        if (lane == 63) wq[wv] = sc;
        __syncthreads();
        unsigned woff = 0;
        for (int w2 = 0; w2 < wv; ++w2) woff += wq[w2];
        unsigned base0 = woff + sc - tsum;
        #pragma unroll
        for (int i = 0; i < 4; ++i) {
            int r = (tid << 2) + i;
            unsigned pfx = base0 + pre[i];
            rowPS[r] = pfx;
            unsigned c2 = rowCnt[r];
            if (c2) aRowSC[pfx >> 16] = (pfx & 0xFFFFu) | (c2 << 16);
        }
        if (tid == 1023) nrS = (base0 + tsum) >> 16;
    }
    __syncthreads();
    // ---------- B2b ----------
    {
        unsigned pre[4]; unsigned tsum = 0;
        #pragma unroll
        for (int i = 0; i < 4; ++i) {
            unsigned c2 = colCnt[(tid << 2) + i];
            unsigned val = c2 | ((c2 ? 1u : 0u) << 12);
            pre[i] = tsum; tsum += val;
        }
        unsigned sc = tsum;
        for (int o = 1; o < 64; o <<= 1) {
            unsigned n2 = __shfl_up(sc, o);
            if (lane >= o) sc += n2;
        }
        if (lane == 63) wq[wv] = sc;
        __syncthreads();
        unsigned woff = 0;
        for (int w2 = 0; w2 < wv; ++w2) woff += wq[w2];
        unsigned base0 = woff + sc - tsum;
        #pragma unroll
        for (int i = 0; i < 4; ++i) {
            int j = (tid << 2) + i;
            unsigned pfx = base0 + pre[i];
            unsigned c2 = colCnt[j];
            colPS[j] = pfx;
            if (c2) {
                unsigned cc = pfx >> 12;
                aColSC[cc] = (pfx & 0xFFFu) | (c2 << 16);
                aColJ[cc] = (unsigned short)j;
            }
        }
        if (tid == 1023) ncS = (base0 + tsum) >> 12;
    }
    __syncthreads();
    {
        unsigned mcc = 0;
        #pragma unroll
        for (int i = 0; i < 4; ++i) mcc = max(mcc, colCnt[(tid << 2) + i]);
        for (int o = 1; o < 64; o <<= 1) { unsigned t2 = __shfl_xor(mcc, o); mcc = max(mcc, t2); }
        if (lane == 0) smax4[wv] = mcc;
    }
    __syncthreads();
    {
        unsigned mx = 0;
        #pragma unroll
        for (int w2 = 0; w2 < 16; ++w2) mx = max(mx, smax4[w2]);
        if (tid == 0 && mx > 64u) meta_g[0] = 1u;
        if (mx > 64u) return;
    }
    __syncthreads();

    // ---------- B3 ----------
    #pragma unroll
    for (int i = 0; i < 4; ++i) {
        int r = (tid << 2) + i;
        int cnt = rowCnt[r];
        if (!cnt) continue;
        unsigned rps = rowPS[r];
        unsigned rptr = rps & 0xFFFFu, rcomp = rps >> 16;
        const float* tz = top_z + (size_t)r * TOPK;
        const int* tj = top_idx + (size_t)r * TOPK;
        for (int k = 0; k < cnt; ++k) {
            float c = fmaxf(M - tz[k], 0.0f);
            float e = expf(-(c / OT_EPS_F));
            unsigned vb = __float_as_uint(e - FLOORK);
            unsigned j = (unsigned)tj[k];
            unsigned old = atomicAdd(&colPS[j], 1u << 24);
            unsigned cptr = old & 0xFFFu, ccomp = (old >> 12) & 0xFFFu, prior = old >> 24;
            rpack[rptr + (unsigned)k] = (unsigned long long)vb | ((unsigned long long)ccomp << 32);
            cpack[cptr + prior]       = (unsigned long long)vb | ((unsigned long long)rcomp << 32);
        }
    }
    __syncthreads();
    // ---------- B4 ----------
    for (int i = tid; i < 2048; i += 1024) { usm[i] = 1.0f; vsm[i] = 1.0f; }

    const int nr = (int)nrS, nc = (int)ncS;
    unsigned rme[2], cme[2];
    #pragma unroll
    for (int s = 0; s < 2; ++s) {
        int i = tid + (s << 10);
        rme[s] = (i < nr) ? aRowSC[i] : 0u;
        cme[s] = (i < nc) ? aColSC[i] : 0u;
    }
    __syncthreads();

    // ---------- D: 16-wave Sinkhorn, 2 barriers/iter ----------
    float u0 = 1.0f, v0 = 1.0f;
    float SvA = (float)nc;
    for (int it = 0; it < 30; ++it) {
        const float bgu = FLOORK * ((float)(B - nc) * v0 + SvA) + 1e-8f;
        const float u0n = AMASS * rcpf_(bgu);
        float SuP = 0.0f;
        #pragma unroll
        for (int s = 0; s < 2; ++s) {
            unsigned me = rme[s];
            unsigned ct = me >> 16;
            if (ct) {
                unsigned st = me & 0xFFFFu;
                float ss = 0.0f;
                for (unsigned k = 0; k < ct; ++k) {
                    unsigned long long wd = rpack[st + k];
                    ss += __uint_as_float((unsigned)wd) * vsm[(unsigned)(wd >> 32)];
                }
                float u = AMASS * rcpf_(bgu + ss);
                usm[tid + (s << 10)] = u;
                SuP += u;
            }
        }
        SuP = wsum64(SuP);
        if (lane == 0) redA[wv] = SuP;
        __syncthreads();
        float Su = 0.0f;
        #pragma unroll
        for (int w2 = 0; w2 < 16; ++w2) Su += redA[w2];
        const float bgv = FLOORK * ((float)(B - nr) * u0n + Su) + 1e-8f;
        const float v0n = AMASS * rcpf_(bgv);
        float SvP = 0.0f; bool moved = false;
        #pragma unroll
        for (int s = 0; s < 2; ++s) {
            unsigned me = cme[s];
            unsigned ct = me >> 16;
            if (ct) {
                unsigned st = me & 0xFFFFu;
                float ss = 0.0f;
                for (unsigned k = 0; k < ct; ++k) {
                    unsigned long long wd = cpack[st + k];
                    ss += __uint_as_float((unsigned)wd) * usm[(unsigned)(wd >> 32)];
                }
                float vn = AMASS * rcpf_(bgv + ss);
                int i2 = tid + (s << 10);
                float vold = vsm[i2];
                if (fabsf(vn - vold) > EPS_L * vold) moved = true;
                vsm[i2] = vn;
                SvP += vn;
            }
        }
        SvP = wsum64(SvP);
        if (lane == 0) { redB[wv] = SvP; mvf[wv] = (__ballot(moved) != 0ull) ? 1u : 0u; }
        __syncthreads();
        float Sv2 = 0.0f; unsigned mvAll = 0u;
        #pragma unroll
        for (int w2 = 0; w2 < 16; ++w2) { Sv2 += redB[w2]; mvAll |= mvf[w2]; }
        SvA = Sv2;
        const bool conv = (mvAll == 0u) &&
                          (fabsf(v0n - v0) <= EPS_L * v0) &&
                          (fabsf(u0n - u0) <= EPS_L * u0);
        u0 = u0n; v0 = v0n;
        if (conv) break;
    }

    // ---------- epilogue ----------
    {
        float4* vo4 = (float4*)vout;
        const float4 fill = make_float4(v0, v0, v0, v0);
        for (int t2 = tid; t2 < 1024; t2 += 1024) vo4[t2] = fill;
        __syncthreads();
        for (int i = tid; i < nc; i += 1024)
            vout[aColJ[i]] = vsm[i];
    }
}

// ---------------------------------------------------------------------------
// k4_fb: list-free global Sinkhorn fallback (meta[0]==1 only).
// ---------------------------------------------------------------------------
__global__ __launch_bounds__(256) void k4_fb(const unsigned int* __restrict__ meta,
                                             const unsigned int* __restrict__ Mkey,
                                             const float* __restrict__ top_z,
                                             const int* __restrict__ top_idx,
                                             float* __restrict__ evals,
                                             float* __restrict__ gv,
                                             float* __restrict__ ga,
                                             float* __restrict__ gb,
                                             float* __restrict__ vout) {
    if (meta[0] == 0u) return;
    __shared__ float red[4];
    __shared__ float bc;
    const int tid = threadIdx.x, lane = tid & 63, wv = tid >> 6;
    const float M = finv(Mkey[0]);

    for (int c = tid; c < B * TOPK; c += 256) {
        float cc = fmaxf(M - top_z[c], 0.0f);
        float e = 0.0f;
        if (cc < CPRE) {
            float t = expf(-(cc / OT_EPS_F));
            if (t > FLOORK) e = t - FLOORK;
        }
        evals[c] = e;
    }
    for (int i = tid; i < B; i += 256) gv[i] = 1.0f;
    __syncthreads();

    for (int it = 0; it < 30; ++it) {
        float s = 0.0f;
        for (int i = tid; i < B; i += 256) { s += gv[i]; ga[i] = 0.0f; }
        for (int o = 1; o < 64; o <<= 1) s += __shfl_xor(s, o);
        if (lane == 0) red[wv] = s;
        __syncthreads();
        if (tid == 0) bc = red[0] + red[1] + red[2] + red[3];
        __syncthreads();
        const float bgu = FLOORK * bc + 1e-8f;
        for (int c = tid; c < B * TOPK; c += 256) {
            float a = evals[c];
            if (a > 0.0f) atomicAdd(&ga[c >> 5], a * gv[top_idx[c]]);
        }
        __syncthreads();
        float su = 0.0f;
        for (int i = tid; i < B; i += 256) { su += AMASS / (bgu + ga[i]); gb[i] = 0.0f; }
        for (int o = 1; o < 64; o <<= 1) su += __shfl_xor(su, o);
        if (lane == 0) red[wv] = su;
        __syncthreads();
        if (tid == 0) bc = red[0] + red[1] + red[2] + red[3];
        __syncthreads();
        const float bgv = FLOORK * bc + 1e-8f;
        for (int c = tid; c < B * TOPK; c += 256) {
            float a = evals[c];
            if (a > 0.0f) {
                float u = AMASS / (bgu + ga[c >> 5]);
                atomicAdd(&gb[top_idx[c]], a * u);
            }
        }
        __syncthreads();
        for (int i = tid; i < B; i += 256) gv[i] = AMASS / (bgv + gb[i]);
        __syncthreads();
    }
    for (int i = tid; i < B; i += 256) vout[i] = gv[i];
}

// ---------------------------------------------------------------------------
// k5: per row: weights = K*v (u cancels), synthetic negative, normalize,
// dot with text row. Unchanged.
// ---------------------------------------------------------------------------
__global__ __launch_bounds__(256) void k5_synth(const int* __restrict__ top_idx,
                                                const float* __restrict__ top_z,
                                                const unsigned int* __restrict__ Mkey,
                                                const float* __restrict__ v,
                                                const float* __restrict__ image,
                                                const float* __restrict__ text,
                                                float* __restrict__ synth_sim) {
    __shared__ float sw[TOPK];
    __shared__ int   sj[TOPK];
    __shared__ float red[4];
    __shared__ float bcast;

    const int row = blockIdx.x, tid = threadIdx.x;
    const int wid = tid >> 6, lane = tid & 63;
    const float M = finv(Mkey[0]);

    if (tid < 64) {
        float wt = 0.0f;
        if (tid < TOPK) {
            int j = top_idx[(size_t)row * TOPK + tid];
            float z = top_z[(size_t)row * TOPK + tid];
            float c = fmaxf(M - z, 0.0f);
            float K = fmaxf(expf(-(c / OT_EPS_F)), FLOORK);
            wt = K * v[j];
            sj[tid] = j;
            sw[tid] = wt;
        }
        float s = wt;
        for (int off = 32; off; off >>= 1) s += __shfl_down(s, off);
        if (tid == 0) bcast = fmaxf(s, 1e-8f);
    }
    __syncthreads();
    if (tid < TOPK) sw[tid] = sw[tid] / bcast;
    __syncthreads();

    float s0 = 0.0f, s1 = 0.0f;
    for (int t = 0; t < TOPK; ++t) {
        float wv2 = sw[t];
        const float* img = image + (size_t)sj[t] * D;
        s0 += wv2 * img[tid];
        s1 += wv2 * img[tid + 256];
    }
    float nn = s0 * s0 + s1 * s1;
    for (int off = 32; off; off >>= 1) nn += __shfl_down(nn, off);
    if (lane == 0) red[wid] = nn;
    __syncthreads();
    float norm2 = red[0] + red[1] + red[2] + red[3];
    float den = sqrtf(norm2) + 1e-8f;
    float p = (s0 / den) * text[(size_t)row * D + tid] +
              (s1 / den) * text[(size_t)row * D + tid + 256];
    __syncthreads();
    for (int off = 32; off; off >>= 1) p += __shfl_down(p, off);
    if (lane == 0) red[wid] = p;
    __syncthreads();
    if (tid == 0) synth_sim[row] = red[0] + red[1] + red[2] + red[3];
}

// ---------------------------------------------------------------------------
// k78: gate + final combine (scale comes precomputed from kmid block 1).
// ---------------------------------------------------------------------------
__global__ __launch_bounds__(256) void k78_final(const float* __restrict__ scale_g,
                                                 const float* __restrict__ synth_sim,
                                                 const double* __restrict__ base_acc,
                                                 float* __restrict__ out) {
    __shared__ double rs[4];
    __shared__ float rg[4];
    const int tid = threadIdx.x, wid = tid >> 6, lane = tid & 63;
    const float scale = scale_g[0];

    double lsd = 0.0; float gs = 0.0f;
    #pragma unroll
    for (int t = 0; t < 16; ++t) {
        float sl = scale * synth_sim[tid + (t << 8)];
        if (sl > -0.05f) { gs += 1.0f; lsd += (double)softplusf(sl); }
    }
    for (int off = 1; off < 64; off <<= 1) {
        lsd += __shfl_xor(lsd, off);
        gs  += __shfl_xor(gs, off);
    }
    if (lane == 0) { rs[wid] = lsd; rg[wid] = gs; }
    __syncthreads();
    if (tid == 0) {
        double L = rs[0] + rs[1] + rs[2] + rs[3];
        float  G = rg[0] + rg[1] + rg[2] + rg[3];
        double base = base_acc[0] / ((double)B * (double)B);
        double synth = (G > 0.0f) ? (L / ((double)G + 1e-8)) : 0.0;
        out[0] = (float)(base + 0.5 * synth);
    }
}

extern "C" void kernel_launch(void* const* d_in, const int* in_sizes, int n_in,
                              void* d_out, int out_size, void* d_ws, size_t ws_size,
                              hipStream_t stream) {
    const float* logits = (const float*)d_in[0];
    const float* text   = (const float*)d_in[1];
    const float* image  = (const float*)d_in[2];
    const float* bias   = (const float*)d_in[3];

    char* ws = (char*)d_ws;
    double*       base_acc = (double*)(ws + 0);
    unsigned int* mcount   = (unsigned int*)(ws + 8);
    unsigned int* Mkey     = (unsigned int*)(ws + 12);
    unsigned int* meta     = (unsigned int*)(ws + 16);
    float*        scale_g  = (float*)(ws + 32);
    unsigned int* flags    = (unsigned int*)(ws + 64);            // 16 KB
    float*        rowsum   = (float*)(ws + 64 + 16384);
    unsigned int* rowmaxk  = (unsigned int*)(rowsum + B);
    float*        v        = (float*)(rowmaxk + B);
    float*        sim      = v + B;
    float*        ratio    = sim + B;
    float*        gv       = ratio + B;
    float*        ga       = gv + B;
    float*        gb       = ga + B;
    int*          top_idx  = (int*)(gb + B);
    float*        top_z    = (float*)(top_idx + (size_t)B * TOPK);
    float*        evals    = (float*)(top_z + (size_t)B * TOPK);

    // zero: header + flags (k1_fallback gating)
    (void)hipMemsetAsync(ws, 0, 64 + 16384, stream);

    k1_row     <<<B / 4, 256, 0, stream>>>(logits, text, image, bias, rowsum, rowmaxk,
                                           top_idx, top_z, ratio, flags);
    k1_fallback<<<B, 256, 0, stream>>>(logits, bias, flags, top_idx, top_z);
    kmid       <<<2, 1024, 0, stream>>>(rowsum, rowmaxk, top_z, top_idx, ratio,
                                        Mkey, base_acc, mcount, meta, scale_g, v);
    k4_fb      <<<1, 256, 0, stream>>>(meta, Mkey, top_z, top_idx, evals, gv, ga, gb, v);
    k5_synth   <<<B, 256, 0, stream>>>(top_idx, top_z, Mkey, v, image, text, sim);
    k78_final  <<<1, 256, 0, stream>>>(scale_g, sim, base_acc, (float*)d_out);
}